// Round 9
// baseline (675.157 us; speedup 1.0000x reference)
//
#include <hip/hip_runtime.h>

#define LL 4096
#define DMODEL 1024
#define DINNER 2048
#define NHEADS 32
#define DSTATE 128
#define DINPROJ 4384
#define NZX 4352           // zxbh bf16 row stride (z 2048 + xBC 2304)
#define CONVDIM 2304
#define ROWS 8192
#define Q 64               // scan sub-chunk
#define NCS 64             // chunks per sequence (LL/Q)
#define XCSEQ ((size_t)LL*CONVDIM)        // y-buffer elems per seq
#define LGSEQ ((size_t)NHEADS*NCS*Q)      // lgbuf elems per seq

typedef __attribute__((ext_vector_type(8))) __bf16 bf16x8;
typedef __attribute__((ext_vector_type(4))) float f32x4;

__device__ __forceinline__ float bf2f(ushort u){ union{uint i;float f;} v; v.i=(uint)u<<16; return v.f; }
__device__ __forceinline__ ushort f2bf(float f){ union{float f;uint i;} v; v.f=f; uint r=v.i+0x7fffu+((v.i>>16)&1u); return (ushort)(r>>16); }

// ---- all f32->bf16 conversions in one launch (x | in_proj_w pad | out_proj_w) ----
__global__ __launch_bounds__(256) void cvt_all(
    const float4* __restrict__ x, uint4* __restrict__ xbf,
    const float4* __restrict__ ipw, ushort4* __restrict__ Wp,
    const float4* __restrict__ opw, uint4* __restrict__ opwb){
  int b = blockIdx.x, tid = threadIdx.x;
  if (b < 4096){
    long t = (long)b*256 + tid;
    float4 a = x[t*2], bb = x[t*2+1];
    ushort u[8] = { f2bf(a.x),f2bf(a.y),f2bf(a.z),f2bf(a.w),
                    f2bf(bb.x),f2bf(bb.y),f2bf(bb.z),f2bf(bb.w) };
    xbf[t] = *(uint4*)u;
  } else if (b < 4096 + 4480){
    int row = b - 4096;
    ushort4 o = make_ushort4(0,0,0,0);
    if (row < DINPROJ){
      float4 f = ipw[(size_t)row*256 + tid];
      o = make_ushort4(f2bf(f.x), f2bf(f.y), f2bf(f.z), f2bf(f.w));
    }
    Wp[(size_t)row*256 + tid] = o;
  } else {
    long t = (long)(b - 8576)*256 + tid;
    float4 a = opw[t*2], bb = opw[t*2+1];
    ushort u[8] = { f2bf(a.x),f2bf(a.y),f2bf(a.z),f2bf(a.w),
                    f2bf(bb.x),f2bf(bb.y),f2bf(bb.z),f2bf(bb.w) };
    opwb[t] = *(uint4*)u;
  }
}

// ---- async global->LDS, 16B per lane ----
__device__ __forceinline__ void gld16(const void* g, void* l){
  __builtin_amdgcn_global_load_lds((const __attribute__((address_space(1))) void*)g,
                                   (__attribute__((address_space(3))) void*)l, 16, 0, 0);
}

#define GBM 128
#define GBN 128
#define GBK 32

// ---- 128^2 bf16 MFMA GEMM: C[m,n] = A[clamp(grow0+m)][:K] . W[n][:K] ----
// n-blocks with n0 >= NZX write f32 to Cdt (dt columns, ldc 128).
__global__ __launch_bounds__(256) void gemm_tile(
    const ushort* __restrict__ A, int lda, long grow0, long rowmax,
    const ushort* __restrict__ W, int ldw,
    void* __restrict__ Cv, int ldc, int K, int obf, int swz, int q, int r,
    float* __restrict__ Cdt){
  __shared__ __align__(16) ushort As[2][GBM*GBK];
  __shared__ __align__(16) ushort Bs[2][GBN*GBK];
  const int tid = threadIdx.x;
  const int lane = tid & 63, wave = tid >> 6;
  const int wm = wave >> 1, wn = wave & 1;
  int bx, by;
  if (swz){
    int wgid = blockIdx.y * gridDim.x + blockIdx.x;
    int xcd = wgid & 7, i = wgid >> 3;
    int vid = (xcd < r) ? xcd*(q+1) + i : r*(q+1) + (xcd - r)*q + i;
    int rows = gridDim.y;
    if (((rows & 7) == 0) && (r == 0)){
      int rp = rows >> 3;
      int lv = vid - xcd*q;
      by = xcd*rp + (lv % rp);      // XCD owns contiguous m-band
      bx = lv / rp;                 // sweep n within band (A-band L2-resident)
    } else { by = vid / (int)gridDim.x; bx = vid % (int)gridDim.x; }
  } else { bx = blockIdx.x; by = blockIdx.y; }
  const int m0 = by * GBM, n0 = bx * GBN;

  const int srow = lane >> 2;
  const int scol = (((lane & 3) ^ ((lane >> 3) & 3)) * 8);
  long ra0 = grow0 + m0 + 16*wave + srow;      if (ra0 < 0) ra0 = 0; if (ra0 > rowmax) ra0 = rowmax;
  long ra1 = grow0 + m0 + 64 + 16*wave + srow; if (ra1 < 0) ra1 = 0; if (ra1 > rowmax) ra1 = rowmax;
  const ushort* gA0 = A + ra0*(long)lda + scol;
  const ushort* gA1 = A + ra1*(long)lda + scol;
  const ushort* gB0 = W + (size_t)(n0 + 16*wave + srow)*ldw + scol;
  const ushort* gB1 = W + (size_t)(n0 + 64 + 16*wave + srow)*ldw + scol;
  ushort* lA0 = &As[0][0] + (16*wave)*GBK;
  ushort* lA1 = &As[0][0] + (64 + 16*wave)*GBK;
  ushort* lB0 = &Bs[0][0] + (16*wave)*GBK;
  ushort* lB1 = &Bs[0][0] + (64 + 16*wave)*GBK;

  const int fr = lane & 15, quad = lane >> 4;
  const int es = ((quad ^ ((fr >> 1) & 3)) * 8);
  f32x4 acc[4][4] = {};

#define STAGE(buf, ko) { \
    gld16(gA0 + (ko), lA0 + (buf)*(GBM*GBK)); \
    gld16(gA1 + (ko), lA1 + (buf)*(GBM*GBK)); \
    gld16(gB0 + (ko), lB0 + (buf)*(GBN*GBK)); \
    gld16(gB1 + (ko), lB1 + (buf)*(GBN*GBK)); }

  STAGE(0, 0);
  __syncthreads();
  int cur = 0;
  const int nst = K / GBK;
  for (int s = 0; s < nst; ++s){
    if (s + 1 < nst) STAGE(cur^1, (s+1)*GBK);
    const ushort* Ab = &As[cur][0];
    const ushort* Bb = &Bs[cur][0];
    bf16x8 af[4], bw[4];
    #pragma unroll
    for (int i=0;i<4;i++) af[i] = *(const bf16x8*)(Ab + (wm*64 + i*16 + fr)*GBK + es);
    #pragma unroll
    for (int j=0;j<4;j++) bw[j] = *(const bf16x8*)(Bb + (wn*64 + j*16 + fr)*GBK + es);
    #pragma unroll
    for (int i=0;i<4;i++)
      #pragma unroll
      for (int j=0;j<4;j++)
        acc[i][j] = __builtin_amdgcn_mfma_f32_16x16x32_bf16(af[i], bw[j], acc[i][j], 0,0,0);
    if (s + 1 < nst){ __syncthreads(); cur ^= 1; }
  }
#undef STAGE
  if (Cdt && n0 >= NZX){
    int nb = n0 - NZX;
    #pragma unroll
    for (int i=0;i<4;i++)
      #pragma unroll
      for (int j=0;j<4;j++){
        size_t base = (size_t)(m0 + wm*64 + i*16 + quad*4)*128 + (nb + wn*64 + j*16 + fr);
        #pragma unroll
        for (int rr=0;rr<4;rr++)
          Cdt[base + (size_t)rr*128] = acc[i][j][rr];
      }
  } else if (obf){
    ushort* Cb = (ushort*)Cv;
    #pragma unroll
    for (int i=0;i<4;i++)
      #pragma unroll
      for (int j=0;j<4;j++){
        size_t base = (size_t)(m0 + wm*64 + i*16 + quad*4)*ldc + (n0 + wn*64 + j*16 + fr);
        #pragma unroll
        for (int rr=0;rr<4;rr++)
          Cb[base + (size_t)rr*ldc] = f2bf(acc[i][j][rr]);
      }
  } else {
    float* Cf = (float*)Cv;
    #pragma unroll
    for (int i=0;i<4;i++)
      #pragma unroll
      for (int j=0;j<4;j++){
        size_t base = (size_t)(m0 + wm*64 + i*16 + quad*4)*ldc + (n0 + wn*64 + j*16 + fr);
        #pragma unroll
        for (int rr=0;rr<4;rr++)
          Cf[base + (size_t)rr*ldc] = acc[i][j][rr];
      }
  }
}

// ---- fused conv helper: 4-tap depthwise conv + SiLU for 16 channels ----
// rv[j] = two uint4 (16 bf16) of row (l-3+j); ch0 = channel base.
__device__ __forceinline__ void conv16(const uint4 rv[4][2],
    const float* __restrict__ cw, const float* __restrict__ cb,
    int ch0, float out[16]){
  #pragma unroll
  for (int i=0;i<16;i++){
    int ch = ch0 + i;
    float4 cwv = *(const float4*)(cw + ch*4);
    float a = cb[ch];
    #pragma unroll
    for (int j=0;j<4;j++){
      const ushort* us = (const ushort*)&rv[j][0];
      a = fmaf(bf2f(us[i]), (&cwv.x)[j], a);
    }
    out[i] = a / (1.f + expf(-a));
  }
}

// ---- load 4 rows x 16 ch (32B) with left-boundary zero guard ----
__device__ __forceinline__ void ldrows(const ushort* __restrict__ rbase, int l,
    uint4 rv[4][2]){
  #pragma unroll
  for (int j=0;j<4;j++){
    if (l - 3 + j >= 0){
      rv[j][0] = *(const uint4*)(rbase + (size_t)j*NZX);
      rv[j][1] = *(const uint4*)(rbase + (size_t)j*NZX + 8);
    } else { rv[j][0] = make_uint4(0,0,0,0); rv[j][1] = make_uint4(0,0,0,0); }
  }
}

// ---- scan phase 1 (conv fused): decay prefix + G = X^T.Bw; blockIdx.z = seq ----
__global__ __launch_bounds__(256) void scan_pre2(const ushort* __restrict__ zxh,
    long grow0, int l0off,
    const float* __restrict__ dtraw,
    const float* __restrict__ cw, const float* __restrict__ cb,
    const float* __restrict__ dtb, const float* __restrict__ alog,
    ushort* __restrict__ gbuf0, ushort* __restrict__ gbuf1,
    float* __restrict__ lgbuf0, int cslot0){
  const int c = blockIdx.x, h = blockIdx.y, z = blockIdx.z;
  const long grow = grow0 + (long)z*LL;
  ushort* gbuf = z ? gbuf1 : gbuf0;
  float* lgbuf = lgbuf0 + (size_t)z*LGSEQ;
  const int cslot = cslot0 + c;
  const int tid = threadIdx.x, lane = tid & 63, w = tid >> 6;
  const int l15 = lane & 15, quad = lane >> 4, kq = quad*8;
  __shared__ float wsx[Q];
  __shared__ __align__(16) ushort XT[64*72];    // [p][s]
  __shared__ __align__(16) ushort BTw[128*72];  // [n][s] weighted; reused as g-stage [64][136]
  const int c0 = c*Q;
  if (tid < 64){
    float xv = dtraw[(size_t)(grow + c0 + tid)*128 + h] + dtb[h];
    float sp = (xv > 20.f) ? xv : log1pf(expf(xv));
    float la = sp * (-expf(alog[h]));
    float v = la;
    #pragma unroll
    for (int off=1; off<64; off<<=1){ float u = __shfl_up(v, off); if (tid >= off) v += u; }
    float tot = __shfl(v, 63);
    wsx[tid] = __expf(tot - v)*sp;
    lgbuf[((size_t)h*NCS + cslot)*Q + tid] = v;
  }
  const int s = tid>>2;
  const int l = l0off + c0 + s;
  const ushort* rowb = zxh + (size_t)(grow + c0 + s - 3)*NZX + DINNER;
  // conv'd X^T staging (16 X-cols of head h per thread)
  { int pb = (tid&3)*16;
    uint4 rv[4][2];
    ldrows(rowb + h*64 + pb, l, rv);
    float o[16];
    conv16(rv, cw, cb, h*64 + pb, o);
    #pragma unroll
    for (int i=0;i<16;i++) XT[(pb+i)*72 + s] = f2bf(o[i]);
  }
  __syncthreads();                 // wsx ready
  // conv'd weighted B staging (2 halves x 16 cols)
  { float wv = wsx[s];
    #pragma unroll
    for (int half=0; half<2; half++){
      int cc = (tid&3)*32 + half*16;          // B col 0..127
      uint4 rv[4][2];
      ldrows(rowb + 2048 + cc, l, rv);
      float o[16];
      conv16(rv, cw, cb, 2048 + cc, o);
      #pragma unroll
      for (int i=0;i<16;i++) BTw[(cc+i)*72 + s] = f2bf(o[i]*wv);
    }
  }
  __syncthreads();
  f32x4 g[8] = {};
  #pragma unroll
  for (int kb=0;kb<2;kb++){
    bf16x8 afr = *(const bf16x8*)(XT + (16*w + l15)*72 + kb*32 + kq);
    #pragma unroll
    for (int j=0;j<8;j++){
      bf16x8 bfr = *(const bf16x8*)(BTw + (16*j + l15)*72 + kb*32 + kq);
      g[j] = __builtin_amdgcn_mfma_f32_16x16x32_bf16(afr, bfr, g[j], 0,0,0);
    }
  }
  __syncthreads();
  ushort* gst = &BTw[0];                 // [p][136] staging, 16B-aligned rows
  #pragma unroll
  for (int j=0;j<8;j++)
    #pragma unroll
    for (int r=0;r<4;r++)
      gst[(16*w + quad*4 + r)*136 + 16*j + l15] = f2bf(g[j][r]);
  __syncthreads();
  { int row = tid >> 2, seg = tid & 3;
    const ushort* gs = gst + row*136 + seg*32;
    uint4 a = *(const uint4*)(gs);
    uint4 b = *(const uint4*)(gs + 8);
    uint4 c2 = *(const uint4*)(gs + 16);
    uint4 d = *(const uint4*)(gs + 24);
    ushort* gdst = gbuf + ((size_t)h*NCS + cslot)*8192 + row*128 + seg*32;
    *(uint4*)gdst = a;
    *(uint4*)(gdst + 8) = b;
    *(uint4*)(gdst + 16) = c2;
    *(uint4*)(gdst + 24) = d;
  }
}

// ---- scan phase 2: sequential carry, IN-PLACE over gbuf; blockIdx.z = seq ----
__global__ __launch_bounds__(256) void scan_carry2(ushort* __restrict__ g0p,
    ushort* __restrict__ g1p, const float* __restrict__ lgbuf0, int ncs){
  const int qtr = blockIdx.x, h = blockIdx.y, z = blockIdx.z;
  ushort* gh = z ? g1p : g0p;
  const float* lgbuf = lgbuf0 + (size_t)z*LGSEQ;
  const int tid = threadIdx.x;
  __shared__ float es[NCS];
  if (tid < ncs) es[tid] = __expf(lgbuf[((size_t)h*NCS + tid)*Q + 63]);
  __syncthreads();
  float hreg[8] = {0.f,0.f,0.f,0.f,0.f,0.f,0.f,0.f};
  ushort* p0 = gh + (size_t)h*NCS*8192 + qtr*2048 + tid*8;
  uint4 g0 = *(const uint4*)p0;
  uint4 g1 = *(const uint4*)(p0 + 8192);
  for (int c = 0; c < ncs; ++c){
    ushort* pc = p0 + (size_t)c*8192;
    uint4 gc = g0; g0 = g1;
    if (c + 2 < ncs) g1 = *(const uint4*)(pc + 2*8192);
    ushort u[8];
    #pragma unroll
    for (int i=0;i<8;i++) u[i] = f2bf(hreg[i]);
    *(uint4*)pc = *(uint4*)u;                     // h_init(c) overwrites g(c)
    float e = es[c];
    const ushort* gs = (const ushort*)&gc;
    #pragma unroll
    for (int i=0;i<8;i++) hreg[i] = fmaf(hreg[i], e, bf2f(gs[i]));
  }
}

// ---- scan phase 3 (conv fused): y = els*(C.h_init) + P.X + Dp*x -> yb; blockIdx.z = seq ----
__global__ __launch_bounds__(256) void scan_y2(const ushort* __restrict__ zxh,
    long grow0, int l0off,
    const float* __restrict__ dtraw,
    const float* __restrict__ cw, const float* __restrict__ cb,
    const float* __restrict__ dtb, const float* __restrict__ alog,
    const float* __restrict__ lgbuf0, const ushort* __restrict__ gbuf0,
    const ushort* __restrict__ gbuf1, const float* __restrict__ Dp,
    ushort* __restrict__ yb0, int cslot0){
  const int c = blockIdx.x, h = blockIdx.y, z = blockIdx.z;
  const long grow = grow0 + (long)z*LL;
  const ushort* gbuf = z ? gbuf1 : gbuf0;
  const float* lgbuf = lgbuf0 + (size_t)z*LGSEQ;
  ushort* yb = yb0 + (size_t)z*XCSEQ;
  const int cslot = cslot0 + c;
  const int tid = threadIdx.x, lane = tid & 63, w = tid >> 6;
  const int l15 = lane & 15, quad = lane >> 4, kq = quad*8;
  __shared__ float lg[Q], dts[Q], els[Q];
  __shared__ __align__(16) ushort XT[64*72];    // conv'd X^T [p][s]
  __shared__ __align__(16) ushort Cc[64*136];   // conv'd C rows [s][128+pad]
  __shared__ __align__(16) ushort BP[64*136];   // conv'd B rows; then Ps [t][72]; then y-stage
  const int c0 = c*Q;
  if (tid < 64){
    float v = lgbuf[((size_t)h*NCS + cslot)*Q + tid];
    lg[tid] = v;
    els[tid] = __expf(v);
    float xv = dtraw[(size_t)(grow + c0 + tid)*128 + h] + dtb[h];
    dts[tid] = (xv > 20.f) ? xv : log1pf(expf(xv));
  }
  const int s = tid>>2;
  const int l = l0off + c0 + s;
  const ushort* rowb = zxh + (size_t)(grow + c0 + s - 3)*NZX + DINNER;
  // conv'd X^T (16 X-cols of head h)
  { int pb = (tid&3)*16;
    uint4 rv[4][2];
    ldrows(rowb + h*64 + pb, l, rv);
    float o[16];
    conv16(rv, cw, cb, h*64 + pb, o);
    #pragma unroll
    for (int i=0;i<16;i++) XT[(pb+i)*72 + s] = f2bf(o[i]);
  }
  // conv'd B rows -> BP [s][136]; C rows -> Cc [s][136]
  #pragma unroll
  for (int half=0; half<2; half++){
    int cc = (tid&3)*32 + half*16;
    uint4 rv[4][2];
    float o[16];
    ldrows(rowb + 2048 + cc, l, rv);
    conv16(rv, cw, cb, 2048 + cc, o);
    #pragma unroll
    for (int i=0;i<16;i++) BP[s*136 + cc + i] = f2bf(o[i]);
    ldrows(rowb + 2176 + cc, l, rv);
    conv16(rv, cw, cb, 2176 + cc, o);
    #pragma unroll
    for (int i=0;i<16;i++) Cc[s*136 + cc + i] = f2bf(o[i]);
  }
  __syncthreads();
  // S = C.B^T from LDS
  f32x4 sac[4] = {};
  #pragma unroll
  for (int kb=0;kb<4;kb++){
    bf16x8 afr = *(const bf16x8*)(Cc + (16*w + l15)*136 + kb*32 + kq);
    #pragma unroll
    for (int j=0;j<4;j++){
      bf16x8 bfr = *(const bf16x8*)(BP + (16*j + l15)*136 + kb*32 + kq);
      sac[j] = __builtin_amdgcn_mfma_f32_16x16x32_bf16(afr, bfr, sac[j], 0,0,0);
    }
  }
  __syncthreads();                 // all B reads done; BP becomes Ps
  #pragma unroll
  for (int j=0;j<4;j++){
    int ss = 16*j + l15;
    float lgs = lg[ss], dtss = dts[ss];
    #pragma unroll
    for (int r=0;r<4;r++){
      int t = 16*w + quad*4 + r;
      float val = (t >= ss) ? sac[j][r]*__expf(lg[t]-lgs)*dtss : 0.f;
      BP[t*72 + ss] = f2bf(val);   // Ps
    }
  }
  __syncthreads();
  float yv[4][4];
  {
    const float dph = Dp[h];
    bf16x8 hb[4], xb[2];
    const ushort* hrow = gbuf + ((size_t)h*NCS + cslot)*8192 + (16*w + l15)*128;
    #pragma unroll
    for (int kb=0;kb<4;kb++) hb[kb] = *(const bf16x8*)(hrow + kb*32 + kq);
    #pragma unroll
    for (int kb=0;kb<2;kb++) xb[kb] = *(const bf16x8*)(XT + (16*w + l15)*72 + kb*32 + kq);
    #pragma unroll
    for (int i=0;i<4;i++){
      f32x4 y2 = {};
      #pragma unroll
      for (int kb=0;kb<4;kb++){
        bf16x8 afr = *(const bf16x8*)(Cc + (16*i + l15)*136 + kb*32 + kq);
        y2 = __builtin_amdgcn_mfma_f32_16x16x32_bf16(afr, hb[kb], y2, 0,0,0);
      }
      f32x4 y1 = {};
      #pragma unroll
      for (int kb=0;kb<2;kb++){
        bf16x8 afr = *(const bf16x8*)(BP + (16*i + l15)*72 + kb*32 + kq);
        y1 = __builtin_amdgcn_mfma_f32_16x16x32_bf16(afr, xb[kb], y1, 0,0,0);
      }
      int p = 16*w + l15;
      #pragma unroll
      for (int r=0;r<4;r++){
        int t = 16*i + quad*4 + r;
        float xv = bf2f(XT[p*72 + t]);
        yv[i][r] = y1[r] + els[t]*y2[r] + dph*xv;
      }
    }
  }
  __syncthreads();                 // all Ps reads done; BP becomes y-stage
  {
    int p = 16*w + l15;
    #pragma unroll
    for (int i=0;i<4;i++)
      #pragma unroll
      for (int r=0;r<4;r++)
        BP[(16*i + quad*4 + r)*72 + p] = f2bf(yv[i][r]);
  }
  __syncthreads();
  { int t = tid >> 2, seg = tid & 3;
    uint4 a = *(const uint4*)(BP + t*72 + seg*16);
    uint4 b = *(const uint4*)(BP + t*72 + seg*16 + 8);
    ushort* od = yb + (size_t)(c0 + t)*CONVDIM + h*64 + seg*16;
    *(uint4*)od = a;
    *(uint4*)(od + 8) = b;
  }
}

// ---- y(in yb) *= silu(z); RMSNorm * nw -> zxbh x-region; blockIdx.y = seq ----
__global__ __launch_bounds__(256) void gate_norm2(const ushort* __restrict__ ybase0,
    const ushort* __restrict__ zbase0, ushort* __restrict__ obase0,
    const float* __restrict__ nw){
  int lr = blockIdx.x, z = blockIdx.y, tid = threadIdx.x;
  const ushort* ybase = ybase0 + (size_t)z*XCSEQ;
  const ushort* zbase = zbase0 + (size_t)z*LL*NZX;
  ushort* obase = obase0 + (size_t)z*LL*NZX;
  int d0 = tid*8;
  const ushort* yrow = ybase + (size_t)lr*CONVDIM;
  const ushort* zrow = zbase + (size_t)lr*NZX;
  uint4 yu = *(const uint4*)(yrow + d0);
  uint4 zu = *(const uint4*)(zrow + d0);
  const ushort* yus = (const ushort*)&yu;
  const ushort* zus = (const ushort*)&zu;
  float y[8]; float ss = 0.f;
  #pragma unroll
  for (int i=0;i<8;i++){
    float zz = bf2f(zus[i]);
    float g = zz / (1.f + expf(-zz));
    float v = bf2f(yus[i]) * g;
    y[i] = v; ss += v*v;
  }
  #pragma unroll
  for (int m=1;m<64;m<<=1) ss += __shfl_xor(ss, m);
  __shared__ float red[4];
  if ((tid & 63) == 0) red[tid>>6] = ss;
  __syncthreads();
  ss = red[0]+red[1]+red[2]+red[3];
  float scale = rsqrtf(ss * (1.f/DINNER) + 1e-5f);
  ushort o[8];
  #pragma unroll
  for (int i=0;i<8;i++)
    o[i] = f2bf(y[i] * scale * nw[d0+i]);
  *(uint4*)(obase + (size_t)lr*NZX + d0) = *(uint4*)o;
}

extern "C" void kernel_launch(void* const* d_in, const int* in_sizes, int n_in,
                              void* d_out, int out_size, void* d_ws, size_t ws_size,
                              hipStream_t stream) {
  const float* x    = (const float*)d_in[0];
  const float* ipw  = (const float*)d_in[1];
  const float* cw   = (const float*)d_in[2];
  const float* cb   = (const float*)d_in[3];
  const float* dtb  = (const float*)d_in[4];
  const float* alog = (const float*)d_in[5];
  const float* Dp   = (const float*)d_in[6];
  const float* nw   = (const float*)d_in[7];
  const float* opw  = (const float*)d_in[8];
  char* ws = (char*)d_ws;
  size_t off = 0;
  ushort* Wp    = (ushort*)(ws + off); off += (size_t)4480*DMODEL*2;     //  9.18 MB
  ushort* opwb  = (ushort*)(ws + off); off += (size_t)DMODEL*DINNER*2;   //  4.19 MB
  float*  dtraw = (float*)(ws + off);  off += (size_t)ROWS*128*4;        //  4.19 MB
  ushort* zxbh  = (ushort*)(ws + off); off += (size_t)ROWS*NZX*2;        // 71.30 MB

  const size_t lg_b  = LGSEQ*4;                     //  0.52 MB per seq
  const size_t yb_b  = XCSEQ*2;                     // 18.87 MB per seq
  const size_t yb_fb = (size_t)1024*CONVDIM*2;      //  4.72 MB per chunk
  const size_t gb_b  = (size_t)NHEADS*NCS*8192*2;   // 33.55 MB per seq

  size_t needA = off + 2*lg_b + 2*yb_b + gb_b;      // ~161.2 MB (gbuf seq1 -> d_out)
  size_t needB = off + lg_b + yb_b + gb_b;          // ~141.8 MB
  int mode = (ws_size >= needA) ? 2 : (ws_size >= needB ? 1 : 0);

  float* lgbuf = (float*)(ws + off); off += (mode == 2) ? 2*lg_b : lg_b;
  ushort* ybuf = (ushort*)(ws + off);
  off += (mode == 2) ? 2*yb_b : (mode == 1 ? yb_b : yb_fb);
  ushort* xbf  = (ushort*)(ws + off);               // dead after gemm1
  ushort* gbuf0 = (ushort*)(ws + off);              // overlays xbf
  ushort* gbuf1 = (mode == 2) ? (ushort*)d_out : gbuf0;   // seq1 state in d_out

  // one conversion launch: x (4096 blks) | padded in_proj_w (4480) | out_proj_w (1024)
  cvt_all<<<9600, 256, 0, stream>>>((const float4*)x, (uint4*)xbf,
                                    (const float4*)ipw, (ushort4*)Wp,
                                    (const float4*)opw, (uint4*)opwb);

  // merged in_proj GEMM incl dt columns: grid (35,64), nwg=2240 (q=280,r=0)
  gemm_tile<<<dim3(35, 64), 256, 0, stream>>>(
      xbf, DMODEL, 0, (long)ROWS-1, Wp, DMODEL,
      zxbh, NZX, DMODEL, 1, 1, 280, 0, dtraw);

  if (mode == 2){
    scan_pre2<<<dim3(NCS, NHEADS, 2), 256, 0, stream>>>(
        zxbh, 0, 0, dtraw, cw, cb, dtb, alog, gbuf0, gbuf1, lgbuf, 0);
    scan_carry2<<<dim3(4, NHEADS, 2), 256, 0, stream>>>(gbuf0, gbuf1, lgbuf, NCS);
    scan_y2<<<dim3(NCS, NHEADS, 2), 256, 0, stream>>>(
        zxbh, 0, 0, dtraw, cw, cb, dtb, alog, lgbuf, gbuf0, gbuf1, Dp, ybuf, 0);
    gate_norm2<<<dim3(LL, 2), 256, 0, stream>>>(ybuf, zxbh, zxbh + DINNER, nw);
  } else if (mode == 1){
    for (int b = 0; b < 2; ++b){
      long row0 = (long)b*LL;
      scan_pre2<<<dim3(NCS, NHEADS, 1), 256, 0, stream>>>(
          zxbh, row0, 0, dtraw, cw, cb, dtb, alog, gbuf0, gbuf0, lgbuf, 0);
      scan_carry2<<<dim3(4, NHEADS, 1), 256, 0, stream>>>(gbuf0, gbuf0, lgbuf, NCS);
      scan_y2<<<dim3(NCS, NHEADS, 1), 256, 0, stream>>>(
          zxbh, row0, 0, dtraw, cw, cb, dtb, alog, lgbuf, gbuf0, gbuf0, Dp, ybuf, 0);
      gate_norm2<<<dim3(LL, 1), 256, 0, stream>>>(
          ybuf, zxbh + (size_t)row0*NZX, zxbh + (size_t)row0*NZX + DINNER, nw);
    }
  } else {
    for (int b = 0; b < 2; ++b){
      long row0 = (long)b*LL;
      for (int ckl = 0; ckl < 4; ++ckl){
        long g0 = row0 + (long)ckl*1024;
        scan_pre2<<<dim3(16, NHEADS, 1), 256, 0, stream>>>(
            zxbh, g0, ckl*1024, dtraw, cw, cb, dtb, alog, gbuf0, gbuf0, lgbuf, ckl*16);
      }
      scan_carry2<<<dim3(4, NHEADS, 1), 256, 0, stream>>>(gbuf0, gbuf0, lgbuf, NCS);
      for (int ckl = 0; ckl < 4; ++ckl){
        long g0 = row0 + (long)ckl*1024;
        scan_y2<<<dim3(16, NHEADS, 1), 256, 0, stream>>>(
            zxbh, g0, ckl*1024, dtraw, cw, cb, dtb, alog, lgbuf, gbuf0, gbuf0, Dp, ybuf, ckl*16);
        gate_norm2<<<dim3(1024, 1), 256, 0, stream>>>(
            ybuf, zxbh + (size_t)g0*NZX, zxbh + (size_t)g0*NZX + DINNER, nw);
      }
    }
  }

  // out-proj GEMM: A = normed y (in zxbh x-region), grid (8,64), nwg=512 (q=64,r=0)
  gemm_tile<<<dim3(8, 64), 256, 0, stream>>>(
      zxbh + DINNER, NZX, 0, (long)ROWS-1, opwb, DINNER,
      (float*)d_out, DMODEL, DINNER, 0, 1, 64, 0, nullptr);
}

// Round 11
// 439.011 us; speedup vs baseline: 1.5379x; 1.5379x over previous
//
#include <hip/hip_runtime.h>

#define LL 4096
#define DMODEL 1024
#define DINNER 2048
#define NHEADS 32
#define DSTATE 128
#define DINPROJ 4384
#define NZX 4352           // zxbh bf16 row stride (z 2048 + xBC 2304)
#define CONVDIM 2304
#define ROWS 8192
#define Q 64               // scan sub-chunk
#define NCS 64             // chunks per sequence (LL/Q)
#define XCSEQ ((size_t)LL*CONVDIM)        // xconv elems per seq
#define LGSEQ ((size_t)NHEADS*NCS*Q)      // lgbuf elems per seq

typedef __attribute__((ext_vector_type(8))) __bf16 bf16x8;
typedef __attribute__((ext_vector_type(4))) float f32x4;

__device__ __forceinline__ float bf2f(ushort u){ union{uint i;float f;} v; v.i=(uint)u<<16; return v.f; }
__device__ __forceinline__ ushort f2bf(float f){ union{float f;uint i;} v; v.f=f; uint r=v.i+0x7fffu+((v.i>>16)&1u); return (ushort)(r>>16); }

// ---- all f32->bf16 conversions in one launch (x | in_proj_w pad | out_proj_w) ----
__global__ __launch_bounds__(256) void cvt_all(
    const float4* __restrict__ x, uint4* __restrict__ xbf,
    const float4* __restrict__ ipw, ushort4* __restrict__ Wp,
    const float4* __restrict__ opw, uint4* __restrict__ opwb){
  int b = blockIdx.x, tid = threadIdx.x;
  if (b < 4096){
    long t = (long)b*256 + tid;
    float4 a = x[t*2], bb = x[t*2+1];
    ushort u[8] = { f2bf(a.x),f2bf(a.y),f2bf(a.z),f2bf(a.w),
                    f2bf(bb.x),f2bf(bb.y),f2bf(bb.z),f2bf(bb.w) };
    xbf[t] = *(uint4*)u;
  } else if (b < 4096 + 4480){
    int row = b - 4096;
    ushort4 o = make_ushort4(0,0,0,0);
    if (row < DINPROJ){
      float4 f = ipw[(size_t)row*256 + tid];
      o = make_ushort4(f2bf(f.x), f2bf(f.y), f2bf(f.z), f2bf(f.w));
    }
    Wp[(size_t)row*256 + tid] = o;
  } else {
    long t = (long)(b - 8576)*256 + tid;
    float4 a = opw[t*2], bb = opw[t*2+1];
    ushort u[8] = { f2bf(a.x),f2bf(a.y),f2bf(a.z),f2bf(a.w),
                    f2bf(bb.x),f2bf(bb.y),f2bf(bb.z),f2bf(bb.w) };
    opwb[t] = *(uint4*)u;
  }
}

// ---- async global->LDS, 16B per lane ----
__device__ __forceinline__ void gld16(const void* g, void* l){
  __builtin_amdgcn_global_load_lds((const __attribute__((address_space(1))) void*)g,
                                   (__attribute__((address_space(3))) void*)l, 16, 0, 0);
}

#define GBM 128
#define GBN 128
#define GBK 32

// ---- 128^2 bf16 MFMA GEMM: C[m,n] = A[clamp(grow0+m)][:K] . W[n][:K] ----
// n-blocks with n0 >= NZX write f32 to Cdt (dt columns, ldc 128).
__global__ __launch_bounds__(256) void gemm_tile(
    const ushort* __restrict__ A, int lda, long grow0, long rowmax,
    const ushort* __restrict__ W, int ldw,
    void* __restrict__ Cv, int ldc, int K, int obf, int swz, int q, int r,
    float* __restrict__ Cdt){
  __shared__ __align__(16) ushort As[2][GBM*GBK];
  __shared__ __align__(16) ushort Bs[2][GBN*GBK];
  const int tid = threadIdx.x;
  const int lane = tid & 63, wave = tid >> 6;
  const int wm = wave >> 1, wn = wave & 1;
  int bx, by;
  if (swz){
    int wgid = blockIdx.y * gridDim.x + blockIdx.x;
    int xcd = wgid & 7, i = wgid >> 3;
    int vid = (xcd < r) ? xcd*(q+1) + i : r*(q+1) + (xcd - r)*q + i;
    int rows = gridDim.y;
    if (((rows & 7) == 0) && (r == 0)){
      int rp = rows >> 3;
      int lv = vid - xcd*q;
      by = xcd*rp + (lv % rp);      // XCD owns contiguous m-band
      bx = lv / rp;                 // sweep n within band (A-band L2-resident)
    } else { by = vid / (int)gridDim.x; bx = vid % (int)gridDim.x; }
  } else { bx = blockIdx.x; by = blockIdx.y; }
  const int m0 = by * GBM, n0 = bx * GBN;

  const int srow = lane >> 2;
  const int scol = (((lane & 3) ^ ((lane >> 3) & 3)) * 8);
  long ra0 = grow0 + m0 + 16*wave + srow;      if (ra0 < 0) ra0 = 0; if (ra0 > rowmax) ra0 = rowmax;
  long ra1 = grow0 + m0 + 64 + 16*wave + srow; if (ra1 < 0) ra1 = 0; if (ra1 > rowmax) ra1 = rowmax;
  const ushort* gA0 = A + ra0*(long)lda + scol;
  const ushort* gA1 = A + ra1*(long)lda + scol;
  const ushort* gB0 = W + (size_t)(n0 + 16*wave + srow)*ldw + scol;
  const ushort* gB1 = W + (size_t)(n0 + 64 + 16*wave + srow)*ldw + scol;
  ushort* lA0 = &As[0][0] + (16*wave)*GBK;
  ushort* lA1 = &As[0][0] + (64 + 16*wave)*GBK;
  ushort* lB0 = &Bs[0][0] + (16*wave)*GBK;
  ushort* lB1 = &Bs[0][0] + (64 + 16*wave)*GBK;

  const int fr = lane & 15, quad = lane >> 4;
  const int es = ((quad ^ ((fr >> 1) & 3)) * 8);
  f32x4 acc[4][4] = {};

#define STAGE(buf, ko) { \
    gld16(gA0 + (ko), lA0 + (buf)*(GBM*GBK)); \
    gld16(gA1 + (ko), lA1 + (buf)*(GBM*GBK)); \
    gld16(gB0 + (ko), lB0 + (buf)*(GBN*GBK)); \
    gld16(gB1 + (ko), lB1 + (buf)*(GBN*GBK)); }

  STAGE(0, 0);
  __syncthreads();
  int cur = 0;
  const int nst = K / GBK;
  for (int s = 0; s < nst; ++s){
    if (s + 1 < nst) STAGE(cur^1, (s+1)*GBK);
    const ushort* Ab = &As[cur][0];
    const ushort* Bb = &Bs[cur][0];
    bf16x8 af[4], bw[4];
    #pragma unroll
    for (int i=0;i<4;i++) af[i] = *(const bf16x8*)(Ab + (wm*64 + i*16 + fr)*GBK + es);
    #pragma unroll
    for (int j=0;j<4;j++) bw[j] = *(const bf16x8*)(Bb + (wn*64 + j*16 + fr)*GBK + es);
    #pragma unroll
    for (int i=0;i<4;i++)
      #pragma unroll
      for (int j=0;j<4;j++)
        acc[i][j] = __builtin_amdgcn_mfma_f32_16x16x32_bf16(af[i], bw[j], acc[i][j], 0,0,0);
    if (s + 1 < nst){ __syncthreads(); cur ^= 1; }
  }
#undef STAGE
  if (Cdt && n0 >= NZX){
    int nb = n0 - NZX;
    #pragma unroll
    for (int i=0;i<4;i++)
      #pragma unroll
      for (int j=0;j<4;j++){
        size_t base = (size_t)(m0 + wm*64 + i*16 + quad*4)*128 + (nb + wn*64 + j*16 + fr);
        #pragma unroll
        for (int rr=0;rr<4;rr++)
          Cdt[base + (size_t)rr*128] = acc[i][j][rr];
      }
  } else if (obf){
    ushort* Cb = (ushort*)Cv;
    #pragma unroll
    for (int i=0;i<4;i++)
      #pragma unroll
      for (int j=0;j<4;j++){
        size_t base = (size_t)(m0 + wm*64 + i*16 + quad*4)*ldc + (n0 + wn*64 + j*16 + fr);
        #pragma unroll
        for (int rr=0;rr<4;rr++)
          Cb[base + (size_t)rr*ldc] = f2bf(acc[i][j][rr]);
      }
  } else {
    float* Cf = (float*)Cv;
    #pragma unroll
    for (int i=0;i<4;i++)
      #pragma unroll
      for (int j=0;j<4;j++){
        size_t base = (size_t)(m0 + wm*64 + i*16 + quad*4)*ldc + (n0 + wn*64 + j*16 + fr);
        #pragma unroll
        for (int rr=0;rr<4;rr++)
          Cf[base + (size_t)rr*ldc] = acc[i][j][rr];
      }
  }
}

// ---- depthwise conv4 + bias + SiLU; 4 rows x 8 ch per thread; blockIdx.y = seq ----
__global__ __launch_bounds__(256) void conv8(const ushort* __restrict__ zxh,
    const float* __restrict__ cw, const float* __restrict__ cb,
    ushort* __restrict__ xconv, int l0, long base){
  int z = blockIdx.y;
  long bb = base + (long)z*LL;
  ushort* xc = xconv + (size_t)z*XCSEQ;
  int id = blockIdx.x*256 + threadIdx.x;
  int g = id % 288, band = id / 288;
  int c = g*8;
  float w[8][4], bias[8];
  #pragma unroll
  for (int i=0;i<8;i++){
    bias[i] = cb[c+i];
    #pragma unroll
    for (int j=0;j<4;j++) w[i][j] = cw[(c+i)*4+j];
  }
  float in[7][8];
  #pragma unroll
  for (int k=0;k<7;k++){
    int lrow = l0 + band*4 - 3 + k;
    if (lrow < 0){
      #pragma unroll
      for (int i=0;i<8;i++) in[k][i] = 0.f;
    } else {
      uint4 v = *(const uint4*)(zxh + (size_t)(bb + band*4 - 3 + k)*NZX + DINNER + c);
      const ushort* us = (const ushort*)&v;
      #pragma unroll
      for (int i=0;i<8;i++) in[k][i] = bf2f(us[i]);
    }
  }
  #pragma unroll
  for (int r=0;r<4;r++){
    ushort o[8];
    #pragma unroll
    for (int i=0;i<8;i++){
      float a = bias[i];
      #pragma unroll
      for (int j=0;j<4;j++) a = fmaf(in[r+j][i], w[i][j], a);
      float v = a / (1.f + expf(-a));
      o[i] = f2bf(v);
    }
    *(uint4*)(xc + (size_t)(band*4 + r)*CONVDIM + c) = *(uint4*)o;
  }
}

// ---- scan phase 1: decay prefix (inline softplus) + G = X^T.Bw; blockIdx.z = seq ----
__global__ __launch_bounds__(256) void scan_pre2(const ushort* __restrict__ xcv0,
    const float* __restrict__ dtraw, long dtrow0,
    const float* __restrict__ dtb, const float* __restrict__ alog,
    ushort* __restrict__ gbuf0, ushort* __restrict__ gbuf1,
    float* __restrict__ lgbuf0, int cslot0){
  const int c = blockIdx.x, h = blockIdx.y, z = blockIdx.z;
  const ushort* xcv = xcv0 + (size_t)z*XCSEQ;
  const long dtr0 = dtrow0 + (long)z*LL;
  ushort* gbuf = z ? gbuf1 : gbuf0;
  float* lgbuf = lgbuf0 + (size_t)z*LGSEQ;
  const int cslot = cslot0 + c;
  const int tid = threadIdx.x, lane = tid & 63, w = tid >> 6;
  const int l15 = lane & 15, quad = lane >> 4, kq = quad*8;
  __shared__ float wsx[Q];
  __shared__ __align__(16) ushort XT[64*72];    // [p][s]
  __shared__ __align__(16) ushort BTw[128*72];  // [n][s], weighted; reused as g-stage
  const int c0 = c*Q;
  if (tid < 64){
    float xv = dtraw[(size_t)(dtr0 + c0 + tid)*128 + h] + dtb[h];
    float sp = (xv > 20.f) ? xv : log1pf(expf(xv));
    float la = sp * (-expf(alog[h]));
    float v = la;
    #pragma unroll
    for (int off=1; off<64; off<<=1){ float u = __shfl_up(v, off); if (tid >= off) v += u; }
    float tot = __shfl(v, 63);
    wsx[tid] = __expf(tot - v)*sp;
    lgbuf[((size_t)h*NCS + cslot)*Q + tid] = v;
  }
  __syncthreads();
  { int s = tid>>2, pb = (tid&3)*16;
    const ushort* src = xcv + (size_t)(c0+s)*CONVDIM + h*64 + pb;
    ushort tmp[16];
    *(uint4*)tmp     = *(const uint4*)src;
    *(uint4*)(tmp+8) = *(const uint4*)(src+8);
    #pragma unroll
    for (int i=0;i<16;i++) XT[(pb+i)*72 + s] = tmp[i];
  }
  { int s = tid>>2, nb4 = (tid&3)*32;
    const ushort* src = xcv + (size_t)(c0+s)*CONVDIM + DINNER + nb4;
    float wv = wsx[s];
    ushort tmp[32];
    #pragma unroll
    for (int v4=0;v4<4;v4++) *(uint4*)(tmp+v4*8) = *(const uint4*)(src+v4*8);
    #pragma unroll
    for (int i=0;i<32;i++) BTw[(nb4+i)*72 + s] = f2bf(bf2f(tmp[i])*wv);
  }
  __syncthreads();
  f32x4 g[8] = {};
  #pragma unroll
  for (int kb=0;kb<2;kb++){
    bf16x8 afr = *(const bf16x8*)(XT + (16*w + l15)*72 + kb*32 + kq);
    #pragma unroll
    for (int j=0;j<8;j++){
      bf16x8 bfr = *(const bf16x8*)(BTw + (16*j + l15)*72 + kb*32 + kq);
      g[j] = __builtin_amdgcn_mfma_f32_16x16x32_bf16(afr, bfr, g[j], 0,0,0);
    }
  }
  __syncthreads();
  ushort* gst = &BTw[0];                 // [p][136] staging, 16B-aligned rows
  #pragma unroll
  for (int j=0;j<8;j++)
    #pragma unroll
    for (int r=0;r<4;r++)
      gst[(16*w + quad*4 + r)*136 + 16*j + l15] = f2bf(g[j][r]);
  __syncthreads();
  { int row = tid >> 2, seg = tid & 3;
    const ushort* gs = gst + row*136 + seg*32;
    uint4 a = *(const uint4*)(gs);
    uint4 b = *(const uint4*)(gs + 8);
    uint4 c2 = *(const uint4*)(gs + 16);
    uint4 d = *(const uint4*)(gs + 24);
    ushort* gdst = gbuf + ((size_t)h*NCS + cslot)*8192 + row*128 + seg*32;
    *(uint4*)gdst = a;
    *(uint4*)(gdst + 8) = b;
    *(uint4*)(gdst + 16) = c2;
    *(uint4*)(gdst + 24) = d;
  }
}

// ---- scan phase 2: sequential carry, IN-PLACE over gbuf; blockIdx.z = seq ----
__global__ __launch_bounds__(256) void scan_carry2(ushort* __restrict__ g0p,
    ushort* __restrict__ g1p, const float* __restrict__ lgbuf0, int ncs){
  const int qtr = blockIdx.x, h = blockIdx.y, z = blockIdx.z;
  ushort* gh = z ? g1p : g0p;
  const float* lgbuf = lgbuf0 + (size_t)z*LGSEQ;
  const int tid = threadIdx.x;
  __shared__ float es[NCS];
  if (tid < ncs) es[tid] = __expf(lgbuf[((size_t)h*NCS + tid)*Q + 63]);
  __syncthreads();
  float hreg[8] = {0.f,0.f,0.f,0.f,0.f,0.f,0.f,0.f};
  ushort* p0 = gh + (size_t)h*NCS*8192 + qtr*2048 + tid*8;
  uint4 g0 = *(const uint4*)p0;
  uint4 g1 = *(const uint4*)(p0 + 8192);
  for (int c = 0; c < ncs; ++c){
    ushort* pc = p0 + (size_t)c*8192;
    uint4 gc = g0; g0 = g1;
    if (c + 2 < ncs) g1 = *(const uint4*)(pc + 2*8192);
    ushort u[8];
    #pragma unroll
    for (int i=0;i<8;i++) u[i] = f2bf(hreg[i]);
    *(uint4*)pc = *(uint4*)u;                     // h_init(c) overwrites g(c)
    float e = es[c];
    const ushort* gs = (const ushort*)&gc;
    #pragma unroll
    for (int i=0;i<8;i++) hreg[i] = fmaf(hreg[i], e, bf2f(gs[i]));
  }
}

// ---- scan phase 3: y = els*(C.h_init) + P.X + Dp*x; blockIdx.z = seq ----
__global__ __launch_bounds__(256) void scan_y2(ushort* __restrict__ xcv0,
    const float* __restrict__ dtraw, long dtrow0,
    const float* __restrict__ dtb, const float* __restrict__ alog,
    const float* __restrict__ lgbuf0, const ushort* __restrict__ gbuf0,
    const ushort* __restrict__ gbuf1, const float* __restrict__ Dp, int cslot0){
  const int c = blockIdx.x, h = blockIdx.y, z = blockIdx.z;
  ushort* xcv = xcv0 + (size_t)z*XCSEQ;
  const long dtr0 = dtrow0 + (long)z*LL;
  const ushort* gbuf = z ? gbuf1 : gbuf0;
  const float* lgbuf = lgbuf0 + (size_t)z*LGSEQ;
  const int cslot = cslot0 + c;
  const int tid = threadIdx.x, lane = tid & 63, w = tid >> 6;
  const int l15 = lane & 15, quad = lane >> 4, kq = quad*8;
  __shared__ float lg[Q], dts[Q], els[Q];
  __shared__ __align__(16) ushort XT[64*72];    // [p][s]
  __shared__ __align__(16) ushort Ps[64*72];    // [t][s]; reused as y-stage
  const int c0 = c*Q;
  if (tid < 64){
    float v = lgbuf[((size_t)h*NCS + cslot)*Q + tid];
    lg[tid] = v;
    els[tid] = __expf(v);
    float xv = dtraw[(size_t)(dtr0 + c0 + tid)*128 + h] + dtb[h];
    dts[tid] = (xv > 20.f) ? xv : log1pf(expf(xv));
  }
  { int s = tid>>2, pb = (tid&3)*16;
    const ushort* src = xcv + (size_t)(c0+s)*CONVDIM + h*64 + pb;
    ushort tmp[16];
    *(uint4*)tmp     = *(const uint4*)src;
    *(uint4*)(tmp+8) = *(const uint4*)(src+8);
    #pragma unroll
    for (int i=0;i<16;i++) XT[(pb+i)*72 + s] = tmp[i];
  }
  __syncthreads();
  {
    const ushort* Crow = xcv + (size_t)(c0 + 16*w + l15)*CONVDIM + DINNER + DSTATE;
    f32x4 sac[4] = {};
    #pragma unroll
    for (int kb=0;kb<4;kb++){
      bf16x8 afr = *(const bf16x8*)(Crow + kb*32 + kq);
      #pragma unroll
      for (int j=0;j<4;j++){
        const ushort* Brow = xcv + (size_t)(c0 + 16*j + l15)*CONVDIM + DINNER;
        bf16x8 bfr = *(const bf16x8*)(Brow + kb*32 + kq);
        sac[j] = __builtin_amdgcn_mfma_f32_16x16x32_bf16(afr, bfr, sac[j], 0,0,0);
      }
    }
    #pragma unroll
    for (int j=0;j<4;j++){
      int s = 16*j + l15;
      float lgs = lg[s], dtss = dts[s];
      #pragma unroll
      for (int r=0;r<4;r++){
        int t = 16*w + quad*4 + r;
        float val = (t >= s) ? sac[j][r]*__expf(lg[t]-lgs)*dtss : 0.f;
        Ps[t*72 + s] = f2bf(val);
      }
    }
  }
  __syncthreads();
  float yv[4][4];
  {
    const float dph = Dp[h];
    bf16x8 hb[4], xb[2];
    const ushort* hrow = gbuf + ((size_t)h*NCS + cslot)*8192 + (16*w + l15)*128;
    #pragma unroll
    for (int kb=0;kb<4;kb++) hb[kb] = *(const bf16x8*)(hrow + kb*32 + kq);
    #pragma unroll
    for (int kb=0;kb<2;kb++) xb[kb] = *(const bf16x8*)(XT + (16*w + l15)*72 + kb*32 + kq);
    #pragma unroll
    for (int i=0;i<4;i++){
      const ushort* Crow = xcv + (size_t)(c0 + 16*i + l15)*CONVDIM + DINNER + DSTATE;
      f32x4 y2 = {};
      #pragma unroll
      for (int kb=0;kb<4;kb++){
        bf16x8 afr = *(const bf16x8*)(Crow + kb*32 + kq);
        y2 = __builtin_amdgcn_mfma_f32_16x16x32_bf16(afr, hb[kb], y2, 0,0,0);
      }
      f32x4 y1 = {};
      #pragma unroll
      for (int kb=0;kb<2;kb++){
        bf16x8 afr = *(const bf16x8*)(Ps + (16*i + l15)*72 + kb*32 + kq);
        y1 = __builtin_amdgcn_mfma_f32_16x16x32_bf16(afr, xb[kb], y1, 0,0,0);
      }
      int p = 16*w + l15;
      #pragma unroll
      for (int r=0;r<4;r++){
        int t = 16*i + quad*4 + r;
        float xv = bf2f(XT[p*72 + t]);
        yv[i][r] = y1[r] + els[t]*y2[r] + dph*xv;
      }
    }
  }
  __syncthreads();
  {
    int p = 16*w + l15;
    #pragma unroll
    for (int i=0;i<4;i++)
      #pragma unroll
      for (int r=0;r<4;r++)
        Ps[(16*i + quad*4 + r)*72 + p] = f2bf(yv[i][r]);
  }
  __syncthreads();
  { int t = tid >> 2, seg = tid & 3;
    uint4 a = *(const uint4*)(Ps + t*72 + seg*16);
    uint4 b = *(const uint4*)(Ps + t*72 + seg*16 + 8);
    ushort* od = xcv + (size_t)(c0 + t)*CONVDIM + h*64 + seg*16;
    *(uint4*)od = a;
    *(uint4*)(od + 8) = b;
  }
}

// ---- y(in xconv x-cols) *= silu(z); RMSNorm * nw -> zxbh x-region; blockIdx.y = seq ----
__global__ __launch_bounds__(256) void gate_norm2(const ushort* __restrict__ ybase0,
    const ushort* __restrict__ zbase0, ushort* __restrict__ obase0,
    const float* __restrict__ nw){
  int lr = blockIdx.x, z = blockIdx.y, tid = threadIdx.x;
  const ushort* ybase = ybase0 + (size_t)z*XCSEQ;
  const ushort* zbase = zbase0 + (size_t)z*LL*NZX;
  ushort* obase = obase0 + (size_t)z*LL*NZX;
  int d0 = tid*8;
  const ushort* yrow = ybase + (size_t)lr*CONVDIM;
  const ushort* zrow = zbase + (size_t)lr*NZX;
  uint4 yu = *(const uint4*)(yrow + d0);
  uint4 zu = *(const uint4*)(zrow + d0);
  const ushort* yus = (const ushort*)&yu;
  const ushort* zus = (const ushort*)&zu;
  float y[8]; float ss = 0.f;
  #pragma unroll
  for (int i=0;i<8;i++){
    float zz = bf2f(zus[i]);
    float g = zz / (1.f + expf(-zz));
    float v = bf2f(yus[i]) * g;
    y[i] = v; ss += v*v;
  }
  #pragma unroll
  for (int m=1;m<64;m<<=1) ss += __shfl_xor(ss, m);
  __shared__ float red[4];
  if ((tid & 63) == 0) red[tid>>6] = ss;
  __syncthreads();
  ss = red[0]+red[1]+red[2]+red[3];
  float scale = rsqrtf(ss * (1.f/DINNER) + 1e-5f);
  ushort o[8];
  #pragma unroll
  for (int i=0;i<8;i++)
    o[i] = f2bf(y[i] * scale * nw[d0+i]);
  *(uint4*)(obase + (size_t)lr*NZX + d0) = *(uint4*)o;
}

extern "C" void kernel_launch(void* const* d_in, const int* in_sizes, int n_in,
                              void* d_out, int out_size, void* d_ws, size_t ws_size,
                              hipStream_t stream) {
  const float* x    = (const float*)d_in[0];
  const float* ipw  = (const float*)d_in[1];
  const float* cw   = (const float*)d_in[2];
  const float* cb   = (const float*)d_in[3];
  const float* dtb  = (const float*)d_in[4];
  const float* alog = (const float*)d_in[5];
  const float* Dp   = (const float*)d_in[6];
  const float* nw   = (const float*)d_in[7];
  const float* opw  = (const float*)d_in[8];
  char* ws = (char*)d_ws;
  size_t off = 0;
  ushort* Wp    = (ushort*)(ws + off); off += (size_t)4480*DMODEL*2;     //  9.18 MB
  ushort* opwb  = (ushort*)(ws + off); off += (size_t)DMODEL*DINNER*2;   //  4.19 MB
  float*  dtraw = (float*)(ws + off);  off += (size_t)ROWS*128*4;        //  4.19 MB
  ushort* zxbh  = (ushort*)(ws + off); off += (size_t)ROWS*NZX*2;        // 71.30 MB

  const size_t lg_b  = LGSEQ*4;                     //  0.52 MB per seq
  const size_t xc_b  = XCSEQ*2;                     // 18.87 MB per seq
  const size_t xc_fb = (size_t)1024*CONVDIM*2;      //  4.72 MB per chunk
  const size_t gb_b  = (size_t)NHEADS*NCS*8192*2;   // 33.55 MB per seq

  size_t needA = off + 2*lg_b + 2*xc_b + gb_b;      // ~161.2 MB (gbuf seq1 -> d_out)
  size_t needB = off + lg_b + xc_b + gb_b;          // ~141.8 MB
  int mode = (ws_size >= needA) ? 2 : (ws_size >= needB ? 1 : 0);

  float* lgbuf = (float*)(ws + off); off += (mode == 2) ? 2*lg_b : lg_b;
  ushort* xconv = (ushort*)(ws + off);
  off += (mode == 2) ? 2*xc_b : (mode == 1 ? xc_b : xc_fb);
  ushort* xbf  = (ushort*)(ws + off);               // dead after gemm1
  ushort* gbuf0 = (ushort*)(ws + off);              // overlays xbf
  ushort* gbuf1 = (mode == 2) ? (ushort*)d_out : gbuf0;   // seq1 state in d_out

  // one conversion launch: x (4096 blks) | padded in_proj_w (4480) | out_proj_w (1024)
  cvt_all<<<9600, 256, 0, stream>>>((const float4*)x, (uint4*)xbf,
                                    (const float4*)ipw, (ushort4*)Wp,
                                    (const float4*)opw, (uint4*)opwb);

  // merged in_proj GEMM incl dt columns: grid (35,64), nwg=2240 (q=280,r=0)
  gemm_tile<<<dim3(35, 64), 256, 0, stream>>>(
      xbf, DMODEL, 0, (long)ROWS-1, Wp, DMODEL,
      zxbh, NZX, DMODEL, 1, 1, 280, 0, dtraw);

  if (mode == 2){
    // both sequences batched per launch: 5 launches total in the scan section
    conv8<<<dim3(288*(LL/4)/256, 2), 256, 0, stream>>>(zxbh, cw, cb, xconv, 0, 0);
    scan_pre2<<<dim3(NCS, NHEADS, 2), 256, 0, stream>>>(
        xconv, dtraw, 0, dtb, alog, gbuf0, gbuf1, lgbuf, 0);
    scan_carry2<<<dim3(4, NHEADS, 2), 256, 0, stream>>>(gbuf0, gbuf1, lgbuf, NCS);
    scan_y2<<<dim3(NCS, NHEADS, 2), 256, 0, stream>>>(
        xconv, dtraw, 0, dtb, alog, lgbuf, gbuf0, gbuf1, Dp, 0);
    gate_norm2<<<dim3(LL, 2), 256, 0, stream>>>(xconv, zxbh, zxbh + DINNER, nw);
  } else if (mode == 1){
    for (int b = 0; b < 2; ++b){
      long row0 = (long)b*LL;
      conv8<<<dim3(288*(LL/4)/256, 1), 256, 0, stream>>>(zxbh, cw, cb, xconv, 0, row0);
      scan_pre2<<<dim3(NCS, NHEADS, 1), 256, 0, stream>>>(
          xconv, dtraw, row0, dtb, alog, gbuf0, gbuf0, lgbuf, 0);
      scan_carry2<<<dim3(4, NHEADS, 1), 256, 0, stream>>>(gbuf0, gbuf0, lgbuf, NCS);
      scan_y2<<<dim3(NCS, NHEADS, 1), 256, 0, stream>>>(
          xconv, dtraw, row0, dtb, alog, lgbuf, gbuf0, gbuf0, Dp, 0);
      gate_norm2<<<dim3(LL, 1), 256, 0, stream>>>(
          xconv, zxbh + (size_t)row0*NZX, zxbh + (size_t)row0*NZX + DINNER, nw);
    }
  } else {
    for (int b = 0; b < 2; ++b){
      long row0 = (long)b*LL;
      for (int ckl = 0; ckl < 4; ++ckl){
        long g0 = row0 + (long)ckl*1024;
        conv8<<<dim3(288*(1024/4)/256, 1), 256, 0, stream>>>(zxbh, cw, cb, xconv, ckl*1024, g0);
        scan_pre2<<<dim3(16, NHEADS, 1), 256, 0, stream>>>(
            xconv, dtraw, g0, dtb, alog, gbuf0, gbuf0, lgbuf, ckl*16);
      }
      scan_carry2<<<dim3(4, NHEADS, 1), 256, 0, stream>>>(gbuf0, gbuf0, lgbuf, NCS);
      for (int ckl = 0; ckl < 4; ++ckl){
        long g0 = row0 + (long)ckl*1024;
        conv8<<<dim3(288*(1024/4)/256, 1), 256, 0, stream>>>(zxbh, cw, cb, xconv, ckl*1024, g0);
        scan_y2<<<dim3(16, NHEADS, 1), 256, 0, stream>>>(
            xconv, dtraw, g0, dtb, alog, lgbuf, gbuf0, gbuf0, Dp, ckl*16);
        gate_norm2<<<dim3(1024, 1), 256, 0, stream>>>(
            xconv, zxbh + (size_t)g0*NZX, zxbh + (size_t)g0*NZX + DINNER, nw);
      }
    }
  }

  // out-proj GEMM: A = normed y (in zxbh x-region), grid (8,64), nwg=512 (q=64,r=0)
  gemm_tile<<<dim3(8, 64), 256, 0, stream>>>(
      zxbh + DINNER, NZX, 0, (long)ROWS-1, opwb, DINNER,
      (float*)d_out, DMODEL, DINNER, 0, 1, 64, 0, nullptr);
}

// Round 12
// 388.978 us; speedup vs baseline: 1.7357x; 1.1286x over previous
//
#include <hip/hip_runtime.h>

#define LL 4096
#define DMODEL 1024
#define DINNER 2048
#define NHEADS 32
#define DSTATE 128
#define DINPROJ 4384
#define NZX 4352           // zxbh bf16 row stride (z 2048 + xBC 2304)
#define CONVDIM 2304
#define ROWS 8192
#define Q 64               // scan sub-chunk
#define NCS 64             // chunks per sequence (LL/Q)
#define XCSEQ ((size_t)LL*CONVDIM)        // xconv elems per seq
#define LGSEQ ((size_t)NHEADS*NCS*Q)      // lgbuf elems per seq

typedef __attribute__((ext_vector_type(8))) __bf16 bf16x8;
typedef __attribute__((ext_vector_type(4))) float f32x4;

__device__ __forceinline__ float bf2f(ushort u){ union{uint i;float f;} v; v.i=(uint)u<<16; return v.f; }
__device__ __forceinline__ ushort f2bf(float f){ union{float f;uint i;} v; v.f=f; uint r=v.i+0x7fffu+((v.i>>16)&1u); return (ushort)(r>>16); }

// ---- all f32->bf16 conversions in one launch (x | in_proj_w pad | out_proj_w) ----
__global__ __launch_bounds__(256) void cvt_all(
    const float4* __restrict__ x, uint4* __restrict__ xbf,
    const float4* __restrict__ ipw, ushort4* __restrict__ Wp,
    const float4* __restrict__ opw, uint4* __restrict__ opwb){
  int b = blockIdx.x, tid = threadIdx.x;
  if (b < 4096){
    long t = (long)b*256 + tid;
    float4 a = x[t*2], bb = x[t*2+1];
    ushort u[8] = { f2bf(a.x),f2bf(a.y),f2bf(a.z),f2bf(a.w),
                    f2bf(bb.x),f2bf(bb.y),f2bf(bb.z),f2bf(bb.w) };
    xbf[t] = *(uint4*)u;
  } else if (b < 4096 + 4480){
    int row = b - 4096;
    ushort4 o = make_ushort4(0,0,0,0);
    if (row < DINPROJ){
      float4 f = ipw[(size_t)row*256 + tid];
      o = make_ushort4(f2bf(f.x), f2bf(f.y), f2bf(f.z), f2bf(f.w));
    }
    Wp[(size_t)row*256 + tid] = o;
  } else {
    long t = (long)(b - 8576)*256 + tid;
    float4 a = opw[t*2], bb = opw[t*2+1];
    ushort u[8] = { f2bf(a.x),f2bf(a.y),f2bf(a.z),f2bf(a.w),
                    f2bf(bb.x),f2bf(bb.y),f2bf(bb.z),f2bf(bb.w) };
    opwb[t] = *(uint4*)u;
  }
}

// ---- async global->LDS, 16B per lane ----
__device__ __forceinline__ void gld16(const void* g, void* l){
  __builtin_amdgcn_global_load_lds((const __attribute__((address_space(1))) void*)g,
                                   (__attribute__((address_space(3))) void*)l, 16, 0, 0);
}

#define GBM 128
#define GBN 128
#define GBK 32

// ---- 128^2 bf16 MFMA GEMM: C[m,n] = A[clamp(grow0+m)][:K] . W[n][:K] ----
// n-blocks with n0 >= NZX write f32 to Cdt (dt columns, ldc 128).
__global__ __launch_bounds__(256) void gemm_tile(
    const ushort* __restrict__ A, int lda, long grow0, long rowmax,
    const ushort* __restrict__ W, int ldw,
    void* __restrict__ Cv, int ldc, int K, int obf, int swz, int q, int r,
    float* __restrict__ Cdt){
  __shared__ __align__(16) ushort As[2][GBM*GBK];
  __shared__ __align__(16) ushort Bs[2][GBN*GBK];
  const int tid = threadIdx.x;
  const int lane = tid & 63, wave = tid >> 6;
  const int wm = wave >> 1, wn = wave & 1;
  int bx, by;
  if (swz){
    int wgid = blockIdx.y * gridDim.x + blockIdx.x;
    int xcd = wgid & 7, i = wgid >> 3;
    int vid = (xcd < r) ? xcd*(q+1) + i : r*(q+1) + (xcd - r)*q + i;
    int rows = gridDim.y;
    if (((rows & 7) == 0) && (r == 0)){
      int rp = rows >> 3;
      int lv = vid - xcd*q;
      by = xcd*rp + (lv % rp);      // XCD owns contiguous m-band
      bx = lv / rp;                 // sweep n within band (A-band L2-resident)
    } else { by = vid / (int)gridDim.x; bx = vid % (int)gridDim.x; }
  } else { bx = blockIdx.x; by = blockIdx.y; }
  const int m0 = by * GBM, n0 = bx * GBN;

  const int srow = lane >> 2;
  const int scol = (((lane & 3) ^ ((lane >> 3) & 3)) * 8);
  long ra0 = grow0 + m0 + 16*wave + srow;      if (ra0 < 0) ra0 = 0; if (ra0 > rowmax) ra0 = rowmax;
  long ra1 = grow0 + m0 + 64 + 16*wave + srow; if (ra1 < 0) ra1 = 0; if (ra1 > rowmax) ra1 = rowmax;
  const ushort* gA0 = A + ra0*(long)lda + scol;
  const ushort* gA1 = A + ra1*(long)lda + scol;
  const ushort* gB0 = W + (size_t)(n0 + 16*wave + srow)*ldw + scol;
  const ushort* gB1 = W + (size_t)(n0 + 64 + 16*wave + srow)*ldw + scol;
  ushort* lA0 = &As[0][0] + (16*wave)*GBK;
  ushort* lA1 = &As[0][0] + (64 + 16*wave)*GBK;
  ushort* lB0 = &Bs[0][0] + (16*wave)*GBK;
  ushort* lB1 = &Bs[0][0] + (64 + 16*wave)*GBK;

  const int fr = lane & 15, quad = lane >> 4;
  const int es = ((quad ^ ((fr >> 1) & 3)) * 8);
  f32x4 acc[4][4] = {};

#define STAGE(buf, ko) { \
    gld16(gA0 + (ko), lA0 + (buf)*(GBM*GBK)); \
    gld16(gA1 + (ko), lA1 + (buf)*(GBM*GBK)); \
    gld16(gB0 + (ko), lB0 + (buf)*(GBN*GBK)); \
    gld16(gB1 + (ko), lB1 + (buf)*(GBN*GBK)); }

  STAGE(0, 0);
  __syncthreads();
  int cur = 0;
  const int nst = K / GBK;
  for (int s = 0; s < nst; ++s){
    if (s + 1 < nst) STAGE(cur^1, (s+1)*GBK);
    const ushort* Ab = &As[cur][0];
    const ushort* Bb = &Bs[cur][0];
    bf16x8 af[4], bw[4];
    #pragma unroll
    for (int i=0;i<4;i++) af[i] = *(const bf16x8*)(Ab + (wm*64 + i*16 + fr)*GBK + es);
    #pragma unroll
    for (int j=0;j<4;j++) bw[j] = *(const bf16x8*)(Bb + (wn*64 + j*16 + fr)*GBK + es);
    #pragma unroll
    for (int i=0;i<4;i++)
      #pragma unroll
      for (int j=0;j<4;j++)
        acc[i][j] = __builtin_amdgcn_mfma_f32_16x16x32_bf16(af[i], bw[j], acc[i][j], 0,0,0);
    if (s + 1 < nst){ __syncthreads(); cur ^= 1; }
  }
#undef STAGE
  if (Cdt && n0 >= NZX){
    int nb = n0 - NZX;
    #pragma unroll
    for (int i=0;i<4;i++)
      #pragma unroll
      for (int j=0;j<4;j++){
        size_t base = (size_t)(m0 + wm*64 + i*16 + quad*4)*128 + (nb + wn*64 + j*16 + fr);
        #pragma unroll
        for (int rr=0;rr<4;rr++)
          Cdt[base + (size_t)rr*128] = acc[i][j][rr];
      }
  } else if (obf){
    ushort* Cb = (ushort*)Cv;
    #pragma unroll
    for (int i=0;i<4;i++)
      #pragma unroll
      for (int j=0;j<4;j++){
        size_t base = (size_t)(m0 + wm*64 + i*16 + quad*4)*ldc + (n0 + wn*64 + j*16 + fr);
        #pragma unroll
        for (int rr=0;rr<4;rr++)
          Cb[base + (size_t)rr*ldc] = f2bf(acc[i][j][rr]);
      }
  } else {
    float* Cf = (float*)Cv;
    #pragma unroll
    for (int i=0;i<4;i++)
      #pragma unroll
      for (int j=0;j<4;j++){
        size_t base = (size_t)(m0 + wm*64 + i*16 + quad*4)*ldc + (n0 + wn*64 + j*16 + fr);
        #pragma unroll
        for (int rr=0;rr<4;rr++)
          Cf[base + (size_t)rr*ldc] = acc[i][j][rr];
      }
  }
}

// ---- depthwise conv4 + bias + SiLU; 4 rows x 8 ch per thread; blockIdx.y = seq ----
__global__ __launch_bounds__(256) void conv8(const ushort* __restrict__ zxh,
    const float* __restrict__ cw, const float* __restrict__ cb,
    ushort* __restrict__ xconv, int l0, long base){
  int z = blockIdx.y;
  long bb = base + (long)z*LL;
  ushort* xc = xconv + (size_t)z*XCSEQ;
  int id = blockIdx.x*256 + threadIdx.x;
  int g = id % 288, band = id / 288;
  int c = g*8;
  float w[8][4], bias[8];
  #pragma unroll
  for (int i=0;i<8;i++){
    bias[i] = cb[c+i];
    #pragma unroll
    for (int j=0;j<4;j++) w[i][j] = cw[(c+i)*4+j];
  }
  float in[7][8];
  #pragma unroll
  for (int k=0;k<7;k++){
    int lrow = l0 + band*4 - 3 + k;
    if (lrow < 0){
      #pragma unroll
      for (int i=0;i<8;i++) in[k][i] = 0.f;
    } else {
      uint4 v = *(const uint4*)(zxh + (size_t)(bb + band*4 - 3 + k)*NZX + DINNER + c);
      const ushort* us = (const ushort*)&v;
      #pragma unroll
      for (int i=0;i<8;i++) in[k][i] = bf2f(us[i]);
    }
  }
  #pragma unroll
  for (int r=0;r<4;r++){
    ushort o[8];
    #pragma unroll
    for (int i=0;i<8;i++){
      float a = bias[i];
      #pragma unroll
      for (int j=0;j<4;j++) a = fmaf(in[r+j][i], w[i][j], a);
      float v = a / (1.f + expf(-a));
      o[i] = f2bf(v);
    }
    *(uint4*)(xc + (size_t)(band*4 + r)*CONVDIM + c) = *(uint4*)o;
  }
}

// ---- scan phase 1: decay prefix (inline softplus) + G = X^T.Bw; blockIdx.z = seq ----
__global__ __launch_bounds__(256) void scan_pre2(const ushort* __restrict__ xcv0,
    const float* __restrict__ dtraw, long dtrow0,
    const float* __restrict__ dtb, const float* __restrict__ alog,
    ushort* __restrict__ gbuf0, ushort* __restrict__ gbuf1,
    float* __restrict__ lgbuf0, int cslot0){
  const int c = blockIdx.x, h = blockIdx.y, z = blockIdx.z;
  const ushort* xcv = xcv0 + (size_t)z*XCSEQ;
  const long dtr0 = dtrow0 + (long)z*LL;
  ushort* gbuf = z ? gbuf1 : gbuf0;
  float* lgbuf = lgbuf0 + (size_t)z*LGSEQ;
  const int cslot = cslot0 + c;
  const int tid = threadIdx.x, lane = tid & 63, w = tid >> 6;
  const int l15 = lane & 15, quad = lane >> 4, kq = quad*8;
  __shared__ float wsx[Q];
  __shared__ __align__(16) ushort XT[64*72];    // [p][s]
  __shared__ __align__(16) ushort BTw[128*72];  // [n][s], weighted; reused as g-stage
  const int c0 = c*Q;
  if (tid < 64){
    float xv = dtraw[(size_t)(dtr0 + c0 + tid)*128 + h] + dtb[h];
    float sp = (xv > 20.f) ? xv : log1pf(expf(xv));
    float la = sp * (-expf(alog[h]));
    float v = la;
    #pragma unroll
    for (int off=1; off<64; off<<=1){ float u = __shfl_up(v, off); if (tid >= off) v += u; }
    float tot = __shfl(v, 63);
    wsx[tid] = __expf(tot - v)*sp;
    lgbuf[((size_t)h*NCS + cslot)*Q + tid] = v;
  }
  __syncthreads();
  { int s = tid>>2, pb = (tid&3)*16;
    const ushort* src = xcv + (size_t)(c0+s)*CONVDIM + h*64 + pb;
    ushort tmp[16];
    *(uint4*)tmp     = *(const uint4*)src;
    *(uint4*)(tmp+8) = *(const uint4*)(src+8);
    #pragma unroll
    for (int i=0;i<16;i++) XT[(pb+i)*72 + s] = tmp[i];
  }
  { int s = tid>>2, nb4 = (tid&3)*32;
    const ushort* src = xcv + (size_t)(c0+s)*CONVDIM + DINNER + nb4;
    float wv = wsx[s];
    ushort tmp[32];
    #pragma unroll
    for (int v4=0;v4<4;v4++) *(uint4*)(tmp+v4*8) = *(const uint4*)(src+v4*8);
    #pragma unroll
    for (int i=0;i<32;i++) BTw[(nb4+i)*72 + s] = f2bf(bf2f(tmp[i])*wv);
  }
  __syncthreads();
  f32x4 g[8] = {};
  #pragma unroll
  for (int kb=0;kb<2;kb++){
    bf16x8 afr = *(const bf16x8*)(XT + (16*w + l15)*72 + kb*32 + kq);
    #pragma unroll
    for (int j=0;j<8;j++){
      bf16x8 bfr = *(const bf16x8*)(BTw + (16*j + l15)*72 + kb*32 + kq);
      g[j] = __builtin_amdgcn_mfma_f32_16x16x32_bf16(afr, bfr, g[j], 0,0,0);
    }
  }
  __syncthreads();
  ushort* gst = &BTw[0];                 // [p][136] staging, 16B-aligned rows
  #pragma unroll
  for (int j=0;j<8;j++)
    #pragma unroll
    for (int r=0;r<4;r++)
      gst[(16*w + quad*4 + r)*136 + 16*j + l15] = f2bf(g[j][r]);
  __syncthreads();
  { int row = tid >> 2, seg = tid & 3;
    const ushort* gs = gst + row*136 + seg*32;
    uint4 a = *(const uint4*)(gs);
    uint4 b = *(const uint4*)(gs + 8);
    uint4 c2 = *(const uint4*)(gs + 16);
    uint4 d = *(const uint4*)(gs + 24);
    ushort* gdst = gbuf + ((size_t)h*NCS + cslot)*8192 + row*128 + seg*32;
    *(uint4*)gdst = a;
    *(uint4*)(gdst + 8) = b;
    *(uint4*)(gdst + 16) = c2;
    *(uint4*)(gdst + 24) = d;
  }
}

// ---- scan phase 2: sequential carry, IN-PLACE over gbuf; blockIdx.z = seq ----
__global__ __launch_bounds__(256) void scan_carry2(ushort* __restrict__ g0p,
    ushort* __restrict__ g1p, const float* __restrict__ lgbuf0, int ncs){
  const int qtr = blockIdx.x, h = blockIdx.y, z = blockIdx.z;
  ushort* gh = z ? g1p : g0p;
  const float* lgbuf = lgbuf0 + (size_t)z*LGSEQ;
  const int tid = threadIdx.x;
  __shared__ float es[NCS];
  if (tid < ncs) es[tid] = __expf(lgbuf[((size_t)h*NCS + tid)*Q + 63]);
  __syncthreads();
  float hreg[8] = {0.f,0.f,0.f,0.f,0.f,0.f,0.f,0.f};
  ushort* p0 = gh + (size_t)h*NCS*8192 + qtr*2048 + tid*8;
  uint4 g0 = *(const uint4*)p0;
  uint4 g1 = *(const uint4*)(p0 + 8192);
  for (int c = 0; c < ncs; ++c){
    ushort* pc = p0 + (size_t)c*8192;
    uint4 gc = g0; g0 = g1;
    if (c + 2 < ncs) g1 = *(const uint4*)(pc + 2*8192);
    ushort u[8];
    #pragma unroll
    for (int i=0;i<8;i++) u[i] = f2bf(hreg[i]);
    *(uint4*)pc = *(uint4*)u;                     // h_init(c) overwrites g(c)
    float e = es[c];
    const ushort* gs = (const ushort*)&gc;
    #pragma unroll
    for (int i=0;i<8;i++) hreg[i] = fmaf(hreg[i], e, bf2f(gs[i]));
  }
}

// ---- scan phase 3: y = els*(C.h_init) + P.X + Dp*x; blockIdx.z = seq ----
// B/C tiles staged ONCE into LDS (coalesced), all MFMA operands from LDS.
__global__ __launch_bounds__(256) void scan_y2(ushort* __restrict__ xcv0,
    const float* __restrict__ dtraw, long dtrow0,
    const float* __restrict__ dtb, const float* __restrict__ alog,
    const float* __restrict__ lgbuf0, const ushort* __restrict__ gbuf0,
    const ushort* __restrict__ gbuf1, const float* __restrict__ Dp, int cslot0){
  const int c = blockIdx.x, h = blockIdx.y, z = blockIdx.z;
  ushort* xcv = xcv0 + (size_t)z*XCSEQ;
  const long dtr0 = dtrow0 + (long)z*LL;
  const ushort* gbuf = z ? gbuf1 : gbuf0;
  const float* lgbuf = lgbuf0 + (size_t)z*LGSEQ;
  const int cslot = cslot0 + c;
  const int tid = threadIdx.x, lane = tid & 63, w = tid >> 6;
  const int l15 = lane & 15, quad = lane >> 4, kq = quad*8;
  __shared__ float lg[Q], dts[Q], els[Q];
  __shared__ __align__(16) ushort XT[64*72];    // [p][s]
  __shared__ __align__(16) ushort Cc[64*136];   // C rows [s][128+pad]
  __shared__ __align__(16) ushort Bp[64*136];   // B rows; then Ps [t][72]; then y-stage
  const int c0 = c*Q;
  if (tid < 64){
    float v = lgbuf[((size_t)h*NCS + cslot)*Q + tid];
    lg[tid] = v;
    els[tid] = __expf(v);
    float xv = dtraw[(size_t)(dtr0 + c0 + tid)*128 + h] + dtb[h];
    dts[tid] = (xv > 20.f) ? xv : log1pf(expf(xv));
  }
  { int s = tid>>2, pb = (tid&3)*16;
    const ushort* src = xcv + (size_t)(c0+s)*CONVDIM + h*64 + pb;
    ushort tmp[16];
    *(uint4*)tmp     = *(const uint4*)src;
    *(uint4*)(tmp+8) = *(const uint4*)(src+8);
    #pragma unroll
    for (int i=0;i<16;i++) XT[(pb+i)*72 + s] = tmp[i];
  }
  // coalesced B/C staging: thread -> (row = tid>>2, seg = tid&3), 64B each
  { int row = tid >> 2, seg = tid & 3;
    const ushort* bsrc = xcv + (size_t)(c0 + row)*CONVDIM + DINNER + seg*32;
    const ushort* csrc = bsrc + DSTATE;
    #pragma unroll
    for (int k=0;k<4;k++){
      *(uint4*)(Bp + row*136 + seg*32 + k*8) = *(const uint4*)(bsrc + k*8);
      *(uint4*)(Cc + row*136 + seg*32 + k*8) = *(const uint4*)(csrc + k*8);
    }
  }
  __syncthreads();
  // S = C.B^T from LDS (row stride 136 -> bank step 4 -> 2-way, free)
  f32x4 sac[4] = {};
  #pragma unroll
  for (int kb=0;kb<4;kb++){
    bf16x8 afr = *(const bf16x8*)(Cc + (16*w + l15)*136 + kb*32 + kq);
    #pragma unroll
    for (int j=0;j<4;j++){
      bf16x8 bfr = *(const bf16x8*)(Bp + (16*j + l15)*136 + kb*32 + kq);
      sac[j] = __builtin_amdgcn_mfma_f32_16x16x32_bf16(afr, bfr, sac[j], 0,0,0);
    }
  }
  __syncthreads();                 // all Bp reads done; Bp becomes Ps
  #pragma unroll
  for (int j=0;j<4;j++){
    int s = 16*j + l15;
    float lgs = lg[s], dtss = dts[s];
    #pragma unroll
    for (int r=0;r<4;r++){
      int t = 16*w + quad*4 + r;
      float val = (t >= s) ? sac[j][r]*__expf(lg[t]-lgs)*dtss : 0.f;
      Bp[t*72 + s] = f2bf(val);    // Ps
    }
  }
  __syncthreads();
  float yv[4][4];
  {
    const float dph = Dp[h];
    bf16x8 hb[4], xb[2];
    const ushort* hrow = gbuf + ((size_t)h*NCS + cslot)*8192 + (16*w + l15)*128;
    #pragma unroll
    for (int kb=0;kb<4;kb++) hb[kb] = *(const bf16x8*)(hrow + kb*32 + kq);
    #pragma unroll
    for (int kb=0;kb<2;kb++) xb[kb] = *(const bf16x8*)(XT + (16*w + l15)*72 + kb*32 + kq);
    #pragma unroll
    for (int i=0;i<4;i++){
      f32x4 y2 = {};
      #pragma unroll
      for (int kb=0;kb<4;kb++){
        bf16x8 afr = *(const bf16x8*)(Cc + (16*i + l15)*136 + kb*32 + kq);
        y2 = __builtin_amdgcn_mfma_f32_16x16x32_bf16(afr, hb[kb], y2, 0,0,0);
      }
      f32x4 y1 = {};
      #pragma unroll
      for (int kb=0;kb<2;kb++){
        bf16x8 afr = *(const bf16x8*)(Bp + (16*i + l15)*72 + kb*32 + kq);
        y1 = __builtin_amdgcn_mfma_f32_16x16x32_bf16(afr, xb[kb], y1, 0,0,0);
      }
      int p = 16*w + l15;
      #pragma unroll
      for (int r=0;r<4;r++){
        int t = 16*i + quad*4 + r;
        float xv = bf2f(XT[p*72 + t]);
        yv[i][r] = y1[r] + els[t]*y2[r] + dph*xv;
      }
    }
  }
  __syncthreads();                 // all Ps reads done; Bp becomes y-stage
  {
    int p = 16*w + l15;
    #pragma unroll
    for (int i=0;i<4;i++)
      #pragma unroll
      for (int r=0;r<4;r++)
        Bp[(16*i + quad*4 + r)*72 + p] = f2bf(yv[i][r]);
  }
  __syncthreads();
  { int t = tid >> 2, seg = tid & 3;
    uint4 a = *(const uint4*)(Bp + t*72 + seg*16);
    uint4 b = *(const uint4*)(Bp + t*72 + seg*16 + 8);
    ushort* od = xcv + (size_t)(c0 + t)*CONVDIM + h*64 + seg*16;
    *(uint4*)od = a;
    *(uint4*)(od + 8) = b;
  }
}

// ---- y(in xconv x-cols) *= silu(z); RMSNorm * nw -> zxbh x-region; blockIdx.y = seq ----
__global__ __launch_bounds__(256) void gate_norm2(const ushort* __restrict__ ybase0,
    const ushort* __restrict__ zbase0, ushort* __restrict__ obase0,
    const float* __restrict__ nw){
  int lr = blockIdx.x, z = blockIdx.y, tid = threadIdx.x;
  const ushort* ybase = ybase0 + (size_t)z*XCSEQ;
  const ushort* zbase = zbase0 + (size_t)z*LL*NZX;
  ushort* obase = obase0 + (size_t)z*LL*NZX;
  int d0 = tid*8;
  const ushort* yrow = ybase + (size_t)lr*CONVDIM;
  const ushort* zrow = zbase + (size_t)lr*NZX;
  uint4 yu = *(const uint4*)(yrow + d0);
  uint4 zu = *(const uint4*)(zrow + d0);
  const ushort* yus = (const ushort*)&yu;
  const ushort* zus = (const ushort*)&zu;
  float y[8]; float ss = 0.f;
  #pragma unroll
  for (int i=0;i<8;i++){
    float zz = bf2f(zus[i]);
    float g = zz / (1.f + expf(-zz));
    float v = bf2f(yus[i]) * g;
    y[i] = v; ss += v*v;
  }
  #pragma unroll
  for (int m=1;m<64;m<<=1) ss += __shfl_xor(ss, m);
  __shared__ float red[4];
  if ((tid & 63) == 0) red[tid>>6] = ss;
  __syncthreads();
  ss = red[0]+red[1]+red[2]+red[3];
  float scale = rsqrtf(ss * (1.f/DINNER) + 1e-5f);
  ushort o[8];
  #pragma unroll
  for (int i=0;i<8;i++)
    o[i] = f2bf(y[i] * scale * nw[d0+i]);
  *(uint4*)(obase + (size_t)lr*NZX + d0) = *(uint4*)o;
}

extern "C" void kernel_launch(void* const* d_in, const int* in_sizes, int n_in,
                              void* d_out, int out_size, void* d_ws, size_t ws_size,
                              hipStream_t stream) {
  const float* x    = (const float*)d_in[0];
  const float* ipw  = (const float*)d_in[1];
  const float* cw   = (const float*)d_in[2];
  const float* cb   = (const float*)d_in[3];
  const float* dtb  = (const float*)d_in[4];
  const float* alog = (const float*)d_in[5];
  const float* Dp   = (const float*)d_in[6];
  const float* nw   = (const float*)d_in[7];
  const float* opw  = (const float*)d_in[8];
  char* ws = (char*)d_ws;
  size_t off = 0;
  ushort* Wp    = (ushort*)(ws + off); off += (size_t)4480*DMODEL*2;     //  9.18 MB
  ushort* opwb  = (ushort*)(ws + off); off += (size_t)DMODEL*DINNER*2;   //  4.19 MB
  float*  dtraw = (float*)(ws + off);  off += (size_t)ROWS*128*4;        //  4.19 MB
  ushort* zxbh  = (ushort*)(ws + off); off += (size_t)ROWS*NZX*2;        // 71.30 MB

  const size_t lg_b  = LGSEQ*4;                     //  0.52 MB per seq
  const size_t xc_b  = XCSEQ*2;                     // 18.87 MB per seq
  const size_t xc_fb = (size_t)1024*CONVDIM*2;      //  4.72 MB per chunk
  const size_t gb_b  = (size_t)NHEADS*NCS*8192*2;   // 33.55 MB per seq

  size_t needA = off + 2*lg_b + 2*xc_b + gb_b;      // ~161.2 MB (gbuf seq1 -> d_out)
  size_t needB = off + lg_b + xc_b + gb_b;          // ~141.8 MB
  int mode = (ws_size >= needA) ? 2 : (ws_size >= needB ? 1 : 0);

  float* lgbuf = (float*)(ws + off); off += (mode == 2) ? 2*lg_b : lg_b;
  ushort* xconv = (ushort*)(ws + off);
  off += (mode == 2) ? 2*xc_b : (mode == 1 ? xc_b : xc_fb);
  ushort* xbf  = (ushort*)(ws + off);               // dead after gemm1
  ushort* gbuf0 = (ushort*)(ws + off);              // overlays xbf
  ushort* gbuf1 = (mode == 2) ? (ushort*)d_out : gbuf0;   // seq1 state in d_out

  // one conversion launch: x (4096 blks) | padded in_proj_w (4480) | out_proj_w (1024)
  cvt_all<<<9600, 256, 0, stream>>>((const float4*)x, (uint4*)xbf,
                                    (const float4*)ipw, (ushort4*)Wp,
                                    (const float4*)opw, (uint4*)opwb);

  // merged in_proj GEMM incl dt columns: grid (35,64), nwg=2240 (q=280,r=0)
  gemm_tile<<<dim3(35, 64), 256, 0, stream>>>(
      xbf, DMODEL, 0, (long)ROWS-1, Wp, DMODEL,
      zxbh, NZX, DMODEL, 1, 1, 280, 0, dtraw);

  if (mode == 2){
    // both sequences batched per launch: 5 launches total in the scan section
    conv8<<<dim3(288*(LL/4)/256, 2), 256, 0, stream>>>(zxbh, cw, cb, xconv, 0, 0);
    scan_pre2<<<dim3(NCS, NHEADS, 2), 256, 0, stream>>>(
        xconv, dtraw, 0, dtb, alog, gbuf0, gbuf1, lgbuf, 0);
    scan_carry2<<<dim3(4, NHEADS, 2), 256, 0, stream>>>(gbuf0, gbuf1, lgbuf, NCS);
    scan_y2<<<dim3(NCS, NHEADS, 2), 256, 0, stream>>>(
        xconv, dtraw, 0, dtb, alog, lgbuf, gbuf0, gbuf1, Dp, 0);
    gate_norm2<<<dim3(LL, 2), 256, 0, stream>>>(xconv, zxbh, zxbh + DINNER, nw);
  } else if (mode == 1){
    for (int b = 0; b < 2; ++b){
      long row0 = (long)b*LL;
      conv8<<<dim3(288*(LL/4)/256, 1), 256, 0, stream>>>(zxbh, cw, cb, xconv, 0, row0);
      scan_pre2<<<dim3(NCS, NHEADS, 1), 256, 0, stream>>>(
          xconv, dtraw, row0, dtb, alog, gbuf0, gbuf0, lgbuf, 0);
      scan_carry2<<<dim3(4, NHEADS, 1), 256, 0, stream>>>(gbuf0, gbuf0, lgbuf, NCS);
      scan_y2<<<dim3(NCS, NHEADS, 1), 256, 0, stream>>>(
          xconv, dtraw, row0, dtb, alog, lgbuf, gbuf0, gbuf0, Dp, 0);
      gate_norm2<<<dim3(LL, 1), 256, 0, stream>>>(
          xconv, zxbh + (size_t)row0*NZX, zxbh + (size_t)row0*NZX + DINNER, nw);
    }
  } else {
    for (int b = 0; b < 2; ++b){
      long row0 = (long)b*LL;
      for (int ckl = 0; ckl < 4; ++ckl){
        long g0 = row0 + (long)ckl*1024;
        conv8<<<dim3(288*(1024/4)/256, 1), 256, 0, stream>>>(zxbh, cw, cb, xconv, ckl*1024, g0);
        scan_pre2<<<dim3(16, NHEADS, 1), 256, 0, stream>>>(
            xconv, dtraw, g0, dtb, alog, gbuf0, gbuf0, lgbuf, ckl*16);
      }
      scan_carry2<<<dim3(4, NHEADS, 1), 256, 0, stream>>>(gbuf0, gbuf0, lgbuf, NCS);
      for (int ckl = 0; ckl < 4; ++ckl){
        long g0 = row0 + (long)ckl*1024;
        scan_y2<<<dim3(16, NHEADS, 1), 256, 0, stream>>>(
            xconv, dtraw, g0, dtb, alog, lgbuf, gbuf0, gbuf0, Dp, ckl*16);
        gate_norm2<<<dim3(1024, 1), 256, 0, stream>>>(
            xconv, zxbh + (size_t)g0*NZX, zxbh + (size_t)g0*NZX + DINNER, nw);
      }
    }
  }

  // out-proj GEMM: A = normed y (in zxbh x-region), grid (8,64), nwg=512 (q=64,r=0)
  gemm_tile<<<dim3(8, 64), 256, 0, stream>>>(
      zxbh + DINNER, NZX, 0, (long)ROWS-1, opwb, DINNER,
      (float*)d_out, DMODEL, DINNER, 0, 1, 64, 0, nullptr);
}

// Round 13
// 384.044 us; speedup vs baseline: 1.7580x; 1.0128x over previous
//
#include <hip/hip_runtime.h>

#define LL 4096
#define DMODEL 1024
#define DINNER 2048
#define NHEADS 32
#define DSTATE 128
#define DINPROJ 4384
#define NZX 4352           // zxbh bf16 row stride (z 2048 + xBC 2304)
#define CONVDIM 2304
#define ROWS 8192
#define Q 64               // scan sub-chunk
#define NCS 64             // chunks per sequence (LL/Q)
#define XCSEQ ((size_t)LL*CONVDIM)        // xconv elems per seq
#define LGSEQ ((size_t)NHEADS*NCS*Q)      // lgbuf elems per seq

typedef __attribute__((ext_vector_type(8))) __bf16 bf16x8;
typedef __attribute__((ext_vector_type(4))) float f32x4;

__device__ __forceinline__ float bf2f(ushort u){ union{uint i;float f;} v; v.i=(uint)u<<16; return v.f; }
__device__ __forceinline__ ushort f2bf(float f){ union{float f;uint i;} v; v.f=f; uint r=v.i+0x7fffu+((v.i>>16)&1u); return (ushort)(r>>16); }

// ---- all f32->bf16 conversions in one launch (x | in_proj_w pad | out_proj_w*nw) ----
__global__ __launch_bounds__(256) void cvt_all(
    const float4* __restrict__ x, uint4* __restrict__ xbf,
    const float4* __restrict__ ipw, ushort4* __restrict__ Wp,
    const float4* __restrict__ opw, uint4* __restrict__ opwb,
    const float* __restrict__ nw){
  int b = blockIdx.x, tid = threadIdx.x;
  if (b < 4096){
    long t = (long)b*256 + tid;
    float4 a = x[t*2], bb = x[t*2+1];
    ushort u[8] = { f2bf(a.x),f2bf(a.y),f2bf(a.z),f2bf(a.w),
                    f2bf(bb.x),f2bf(bb.y),f2bf(bb.z),f2bf(bb.w) };
    xbf[t] = *(uint4*)u;
  } else if (b < 4096 + 4480){
    int row = b - 4096;
    ushort4 o = make_ushort4(0,0,0,0);
    if (row < DINPROJ){
      float4 f = ipw[(size_t)row*256 + tid];
      o = make_ushort4(f2bf(f.x), f2bf(f.y), f2bf(f.z), f2bf(f.w));
    }
    Wp[(size_t)row*256 + tid] = o;
  } else {
    long t = (long)(b - 8576)*256 + tid;
    float4 a = opw[t*2], bb = opw[t*2+1];
    long e0 = t*8;
    float w0 = nw[(e0+0)&2047], w1 = nw[(e0+1)&2047], w2 = nw[(e0+2)&2047], w3 = nw[(e0+3)&2047];
    float w4 = nw[(e0+4)&2047], w5 = nw[(e0+5)&2047], w6 = nw[(e0+6)&2047], w7 = nw[(e0+7)&2047];
    ushort u[8] = { f2bf(a.x*w0),f2bf(a.y*w1),f2bf(a.z*w2),f2bf(a.w*w3),
                    f2bf(bb.x*w4),f2bf(bb.y*w5),f2bf(bb.z*w6),f2bf(bb.w*w7) };
    opwb[t] = *(uint4*)u;
  }
}

// ---- async global->LDS, 16B per lane ----
__device__ __forceinline__ void gld16(const void* g, void* l){
  __builtin_amdgcn_global_load_lds((const __attribute__((address_space(1))) void*)g,
                                   (__attribute__((address_space(3))) void*)l, 16, 0, 0);
}

#define GBM 128
#define GBN 128
#define GBK 32

// ---- 128^2 bf16 MFMA GEMM: C[m,n] = A[clamp(grow0+m)][:K] . W[n][:K] ----
// n-blocks with n0 >= NZX write f32 to Cdt (dt columns, ldc 128).
// rowsc != null: RMSNorm fold — scale[row] = rsqrt(mean(sum32 partials)+eps),
// applied to acc at epilogue (linear in A-row, exact in f32).
__global__ __launch_bounds__(256) void gemm_tile(
    const ushort* __restrict__ A, int lda, long grow0, long rowmax,
    const ushort* __restrict__ W, int ldw,
    void* __restrict__ Cv, int ldc, int K, int obf, int swz, int q, int r,
    float* __restrict__ Cdt, const float* __restrict__ rowsc){
  __shared__ __align__(16) ushort As[2][GBM*GBK];
  __shared__ __align__(16) ushort Bs[2][GBN*GBK];
  __shared__ float scl[128];
  const int tid = threadIdx.x;
  const int lane = tid & 63, wave = tid >> 6;
  const int wm = wave >> 1, wn = wave & 1;
  int bx, by;
  if (swz){
    int wgid = blockIdx.y * gridDim.x + blockIdx.x;
    int xcd = wgid & 7, i = wgid >> 3;
    int vid = (xcd < r) ? xcd*(q+1) + i : r*(q+1) + (xcd - r)*q + i;
    int rows = gridDim.y;
    if (((rows & 7) == 0) && (r == 0)){
      int rp = rows >> 3;
      int lv = vid - xcd*q;
      by = xcd*rp + (lv % rp);      // XCD owns contiguous m-band
      bx = lv / rp;                 // sweep n within band (A-band L2-resident)
    } else { by = vid / (int)gridDim.x; bx = vid % (int)gridDim.x; }
  } else { bx = blockIdx.x; by = blockIdx.y; }
  const int m0 = by * GBM, n0 = bx * GBN;

  const int srow = lane >> 2;
  const int scol = (((lane & 3) ^ ((lane >> 3) & 3)) * 8);
  long ra0 = grow0 + m0 + 16*wave + srow;      if (ra0 < 0) ra0 = 0; if (ra0 > rowmax) ra0 = rowmax;
  long ra1 = grow0 + m0 + 64 + 16*wave + srow; if (ra1 < 0) ra1 = 0; if (ra1 > rowmax) ra1 = rowmax;
  const ushort* gA0 = A + ra0*(long)lda + scol;
  const ushort* gA1 = A + ra1*(long)lda + scol;
  const ushort* gB0 = W + (size_t)(n0 + 16*wave + srow)*ldw + scol;
  const ushort* gB1 = W + (size_t)(n0 + 64 + 16*wave + srow)*ldw + scol;
  ushort* lA0 = &As[0][0] + (16*wave)*GBK;
  ushort* lA1 = &As[0][0] + (64 + 16*wave)*GBK;
  ushort* lB0 = &Bs[0][0] + (16*wave)*GBK;
  ushort* lB1 = &Bs[0][0] + (64 + 16*wave)*GBK;

  const int fr = lane & 15, quad = lane >> 4;
  const int es = ((quad ^ ((fr >> 1) & 3)) * 8);
  f32x4 acc[4][4] = {};

#define STAGE(buf, ko) { \
    gld16(gA0 + (ko), lA0 + (buf)*(GBM*GBK)); \
    gld16(gA1 + (ko), lA1 + (buf)*(GBM*GBK)); \
    gld16(gB0 + (ko), lB0 + (buf)*(GBN*GBK)); \
    gld16(gB1 + (ko), lB1 + (buf)*(GBN*GBK)); }

  STAGE(0, 0);
  if (rowsc && tid < 128){
    long rr = grow0 + m0 + tid; if (rr < 0) rr = 0; if (rr > rowmax) rr = rowmax;
    const float* pr = rowsc + (size_t)rr*128;
    float s = 0.f;
    #pragma unroll
    for (int h=0;h<32;h++) s += pr[h];
    scl[tid] = rsqrtf(s*(1.f/(float)DINNER) + 1e-5f);
  }
  __syncthreads();
  int cur = 0;
  const int nst = K / GBK;
  for (int s = 0; s < nst; ++s){
    if (s + 1 < nst) STAGE(cur^1, (s+1)*GBK);
    const ushort* Ab = &As[cur][0];
    const ushort* Bb = &Bs[cur][0];
    bf16x8 af[4], bw[4];
    #pragma unroll
    for (int i=0;i<4;i++) af[i] = *(const bf16x8*)(Ab + (wm*64 + i*16 + fr)*GBK + es);
    #pragma unroll
    for (int j=0;j<4;j++) bw[j] = *(const bf16x8*)(Bb + (wn*64 + j*16 + fr)*GBK + es);
    #pragma unroll
    for (int i=0;i<4;i++)
      #pragma unroll
      for (int j=0;j<4;j++)
        acc[i][j] = __builtin_amdgcn_mfma_f32_16x16x32_bf16(af[i], bw[j], acc[i][j], 0,0,0);
    if (s + 1 < nst){ __syncthreads(); cur ^= 1; }
  }
#undef STAGE
  if (rowsc){
    #pragma unroll
    for (int i=0;i<4;i++){
      #pragma unroll
      for (int rr=0;rr<4;rr++){
        float sv = scl[wm*64 + i*16 + quad*4 + rr];
        #pragma unroll
        for (int j=0;j<4;j++) acc[i][j][rr] *= sv;
      }
    }
  }
  if (Cdt && n0 >= NZX){
    int nb = n0 - NZX;
    #pragma unroll
    for (int i=0;i<4;i++)
      #pragma unroll
      for (int j=0;j<4;j++){
        size_t base = (size_t)(m0 + wm*64 + i*16 + quad*4)*128 + (nb + wn*64 + j*16 + fr);
        #pragma unroll
        for (int rr=0;rr<4;rr++)
          Cdt[base + (size_t)rr*128] = acc[i][j][rr];
      }
  } else if (obf){
    ushort* Cb = (ushort*)Cv;
    #pragma unroll
    for (int i=0;i<4;i++)
      #pragma unroll
      for (int j=0;j<4;j++){
        size_t base = (size_t)(m0 + wm*64 + i*16 + quad*4)*ldc + (n0 + wn*64 + j*16 + fr);
        #pragma unroll
        for (int rr=0;rr<4;rr++)
          Cb[base + (size_t)rr*ldc] = f2bf(acc[i][j][rr]);
      }
  } else {
    float* Cf = (float*)Cv;
    #pragma unroll
    for (int i=0;i<4;i++)
      #pragma unroll
      for (int j=0;j<4;j++){
        size_t base = (size_t)(m0 + wm*64 + i*16 + quad*4)*ldc + (n0 + wn*64 + j*16 + fr);
        #pragma unroll
        for (int rr=0;rr<4;rr++)
          Cf[base + (size_t)rr*ldc] = acc[i][j][rr];
      }
  }
}

// ---- depthwise conv4 + bias + SiLU; 4 rows x 8 ch per thread; blockIdx.y = seq ----
__global__ __launch_bounds__(256) void conv8(const ushort* __restrict__ zxh,
    const float* __restrict__ cw, const float* __restrict__ cb,
    ushort* __restrict__ xconv, int l0, long base){
  int z = blockIdx.y;
  long bb = base + (long)z*LL;
  ushort* xc = xconv + (size_t)z*XCSEQ;
  int id = blockIdx.x*256 + threadIdx.x;
  int g = id % 288, band = id / 288;
  int c = g*8;
  float w[8][4], bias[8];
  #pragma unroll
  for (int i=0;i<8;i++){
    bias[i] = cb[c+i];
    #pragma unroll
    for (int j=0;j<4;j++) w[i][j] = cw[(c+i)*4+j];
  }
  float in[7][8];
  #pragma unroll
  for (int k=0;k<7;k++){
    int lrow = l0 + band*4 - 3 + k;
    if (lrow < 0){
      #pragma unroll
      for (int i=0;i<8;i++) in[k][i] = 0.f;
    } else {
      uint4 v = *(const uint4*)(zxh + (size_t)(bb + band*4 - 3 + k)*NZX + DINNER + c);
      const ushort* us = (const ushort*)&v;
      #pragma unroll
      for (int i=0;i<8;i++) in[k][i] = bf2f(us[i]);
    }
  }
  #pragma unroll
  for (int r=0;r<4;r++){
    ushort o[8];
    #pragma unroll
    for (int i=0;i<8;i++){
      float a = bias[i];
      #pragma unroll
      for (int j=0;j<4;j++) a = fmaf(in[r+j][i], w[i][j], a);
      float v = a / (1.f + expf(-a));
      o[i] = f2bf(v);
    }
    *(uint4*)(xc + (size_t)(band*4 + r)*CONVDIM + c) = *(uint4*)o;
  }
}

// ---- scan phase 1: decay prefix (inline softplus) + G = X^T.Bw; blockIdx.z = seq ----
__global__ __launch_bounds__(256) void scan_pre2(const ushort* __restrict__ xcv0,
    const float* __restrict__ dtraw, long dtrow0,
    const float* __restrict__ dtb, const float* __restrict__ alog,
    ushort* __restrict__ gbuf0, ushort* __restrict__ gbuf1,
    float* __restrict__ lgbuf0, int cslot0){
  const int c = blockIdx.x, h = blockIdx.y, z = blockIdx.z;
  const ushort* xcv = xcv0 + (size_t)z*XCSEQ;
  const long dtr0 = dtrow0 + (long)z*LL;
  ushort* gbuf = z ? gbuf1 : gbuf0;
  float* lgbuf = lgbuf0 + (size_t)z*LGSEQ;
  const int cslot = cslot0 + c;
  const int tid = threadIdx.x, lane = tid & 63, w = tid >> 6;
  const int l15 = lane & 15, quad = lane >> 4, kq = quad*8;
  __shared__ float wsx[Q];
  __shared__ __align__(16) ushort XT[64*72];    // [p][s]
  __shared__ __align__(16) ushort BTw[128*72];  // [n][s], weighted; reused as g-stage
  const int c0 = c*Q;
  if (tid < 64){
    float xv = dtraw[(size_t)(dtr0 + c0 + tid)*128 + h] + dtb[h];
    float sp = (xv > 20.f) ? xv : log1pf(expf(xv));
    float la = sp * (-expf(alog[h]));
    float v = la;
    #pragma unroll
    for (int off=1; off<64; off<<=1){ float u = __shfl_up(v, off); if (tid >= off) v += u; }
    float tot = __shfl(v, 63);
    wsx[tid] = __expf(tot - v)*sp;
    lgbuf[((size_t)h*NCS + cslot)*Q + tid] = v;
  }
  __syncthreads();
  { int s = tid>>2, pb = (tid&3)*16;
    const ushort* src = xcv + (size_t)(c0+s)*CONVDIM + h*64 + pb;
    ushort tmp[16];
    *(uint4*)tmp     = *(const uint4*)src;
    *(uint4*)(tmp+8) = *(const uint4*)(src+8);
    #pragma unroll
    for (int i=0;i<16;i++) XT[(pb+i)*72 + s] = tmp[i];
  }
  { int s = tid>>2, nb4 = (tid&3)*32;
    const ushort* src = xcv + (size_t)(c0+s)*CONVDIM + DINNER + nb4;
    float wv = wsx[s];
    ushort tmp[32];
    #pragma unroll
    for (int v4=0;v4<4;v4++) *(uint4*)(tmp+v4*8) = *(const uint4*)(src+v4*8);
    #pragma unroll
    for (int i=0;i<32;i++) BTw[(nb4+i)*72 + s] = f2bf(bf2f(tmp[i])*wv);
  }
  __syncthreads();
  f32x4 g[8] = {};
  #pragma unroll
  for (int kb=0;kb<2;kb++){
    bf16x8 afr = *(const bf16x8*)(XT + (16*w + l15)*72 + kb*32 + kq);
    #pragma unroll
    for (int j=0;j<8;j++){
      bf16x8 bfr = *(const bf16x8*)(BTw + (16*j + l15)*72 + kb*32 + kq);
      g[j] = __builtin_amdgcn_mfma_f32_16x16x32_bf16(afr, bfr, g[j], 0,0,0);
    }
  }
  __syncthreads();
  ushort* gst = &BTw[0];                 // [p][136] staging, 16B-aligned rows
  #pragma unroll
  for (int j=0;j<8;j++)
    #pragma unroll
    for (int r=0;r<4;r++)
      gst[(16*w + quad*4 + r)*136 + 16*j + l15] = f2bf(g[j][r]);
  __syncthreads();
  { int row = tid >> 2, seg = tid & 3;
    const ushort* gs = gst + row*136 + seg*32;
    uint4 a = *(const uint4*)(gs);
    uint4 b = *(const uint4*)(gs + 8);
    uint4 c2 = *(const uint4*)(gs + 16);
    uint4 d = *(const uint4*)(gs + 24);
    ushort* gdst = gbuf + ((size_t)h*NCS + cslot)*8192 + row*128 + seg*32;
    *(uint4*)gdst = a;
    *(uint4*)(gdst + 8) = b;
    *(uint4*)(gdst + 16) = c2;
    *(uint4*)(gdst + 24) = d;
  }
}

// ---- scan phase 2: sequential carry, IN-PLACE over gbuf; blockIdx.z = seq ----
__global__ __launch_bounds__(256) void scan_carry2(ushort* __restrict__ g0p,
    ushort* __restrict__ g1p, const float* __restrict__ lgbuf0, int ncs){
  const int qtr = blockIdx.x, h = blockIdx.y, z = blockIdx.z;
  ushort* gh = z ? g1p : g0p;
  const float* lgbuf = lgbuf0 + (size_t)z*LGSEQ;
  const int tid = threadIdx.x;
  __shared__ float es[NCS];
  if (tid < ncs) es[tid] = __expf(lgbuf[((size_t)h*NCS + tid)*Q + 63]);
  __syncthreads();
  float hreg[8] = {0.f,0.f,0.f,0.f,0.f,0.f,0.f,0.f};
  ushort* p0 = gh + (size_t)h*NCS*8192 + qtr*2048 + tid*8;
  uint4 g0 = *(const uint4*)p0;
  uint4 g1 = *(const uint4*)(p0 + 8192);
  for (int c = 0; c < ncs; ++c){
    ushort* pc = p0 + (size_t)c*8192;
    uint4 gc = g0; g0 = g1;
    if (c + 2 < ncs) g1 = *(const uint4*)(pc + 2*8192);
    ushort u[8];
    #pragma unroll
    for (int i=0;i<8;i++) u[i] = f2bf(hreg[i]);
    *(uint4*)pc = *(uint4*)u;                     // h_init(c) overwrites g(c)
    float e = es[c];
    const ushort* gs = (const ushort*)&gc;
    #pragma unroll
    for (int i=0;i<8;i++) hreg[i] = fmaf(hreg[i], e, bf2f(gs[i]));
  }
}

// ---- scan phase 3: y = els*(C.h_init) + P.X + Dp*x, then GATED with silu(z);
// writes gated-y bf16 into xcv x-cols + per-(row,head) sumsq into dtraw cols 64..95.
__global__ __launch_bounds__(256) void scan_y2(ushort* __restrict__ xcv0,
    const ushort* __restrict__ zxh,
    float* __restrict__ dtraw, long dtrow0,
    const float* __restrict__ dtb, const float* __restrict__ alog,
    const float* __restrict__ lgbuf0, const ushort* __restrict__ gbuf0,
    const ushort* __restrict__ gbuf1, const float* __restrict__ Dp, int cslot0){
  const int c = blockIdx.x, h = blockIdx.y, z = blockIdx.z;
  ushort* xcv = xcv0 + (size_t)z*XCSEQ;
  const long dtr0 = dtrow0 + (long)z*LL;
  const ushort* gbuf = z ? gbuf1 : gbuf0;
  const float* lgbuf = lgbuf0 + (size_t)z*LGSEQ;
  const int cslot = cslot0 + c;
  const int tid = threadIdx.x, lane = tid & 63, w = tid >> 6;
  const int l15 = lane & 15, quad = lane >> 4, kq = quad*8;
  __shared__ float lg[Q], dts[Q], els[Q];
  __shared__ __align__(16) ushort XT[64*72];    // [p][s]
  __shared__ __align__(16) ushort Cc[64*136];   // C rows [s][128+pad]
  __shared__ __align__(16) ushort Bp[64*136];   // B rows; then Ps [t][72]; then y-stage
  const int c0 = c*Q;
  if (tid < 64){
    float v = lgbuf[((size_t)h*NCS + cslot)*Q + tid];
    lg[tid] = v;
    els[tid] = __expf(v);
    float xv = dtraw[(size_t)(dtr0 + c0 + tid)*128 + h] + dtb[h];
    dts[tid] = (xv > 20.f) ? xv : log1pf(expf(xv));
  }
  { int s = tid>>2, pb = (tid&3)*16;
    const ushort* src = xcv + (size_t)(c0+s)*CONVDIM + h*64 + pb;
    ushort tmp[16];
    *(uint4*)tmp     = *(const uint4*)src;
    *(uint4*)(tmp+8) = *(const uint4*)(src+8);
    #pragma unroll
    for (int i=0;i<16;i++) XT[(pb+i)*72 + s] = tmp[i];
  }
  // coalesced B/C staging: thread -> (row = tid>>2, seg = tid&3), 64B each
  { int row = tid >> 2, seg = tid & 3;
    const ushort* bsrc = xcv + (size_t)(c0 + row)*CONVDIM + DINNER + seg*32;
    const ushort* csrc = bsrc + DSTATE;
    #pragma unroll
    for (int k=0;k<4;k++){
      *(uint4*)(Bp + row*136 + seg*32 + k*8) = *(const uint4*)(bsrc + k*8);
      *(uint4*)(Cc + row*136 + seg*32 + k*8) = *(const uint4*)(csrc + k*8);
    }
  }
  __syncthreads();
  // S = C.B^T from LDS
  f32x4 sac[4] = {};
  #pragma unroll
  for (int kb=0;kb<4;kb++){
    bf16x8 afr = *(const bf16x8*)(Cc + (16*w + l15)*136 + kb*32 + kq);
    #pragma unroll
    for (int j=0;j<4;j++){
      bf16x8 bfr = *(const bf16x8*)(Bp + (16*j + l15)*136 + kb*32 + kq);
      sac[j] = __builtin_amdgcn_mfma_f32_16x16x32_bf16(afr, bfr, sac[j], 0,0,0);
    }
  }
  __syncthreads();                 // all Bp reads done; Bp becomes Ps
  #pragma unroll
  for (int j=0;j<4;j++){
    int s = 16*j + l15;
    float lgs = lg[s], dtss = dts[s];
    #pragma unroll
    for (int r=0;r<4;r++){
      int t = 16*w + quad*4 + r;
      float val = (t >= s) ? sac[j][r]*__expf(lg[t]-lgs)*dtss : 0.f;
      Bp[t*72 + s] = f2bf(val);    // Ps
    }
  }
  __syncthreads();
  float yv[4][4];
  {
    const float dph = Dp[h];
    bf16x8 hb[4], xb[2];
    const ushort* hrow = gbuf + ((size_t)h*NCS + cslot)*8192 + (16*w + l15)*128;
    #pragma unroll
    for (int kb=0;kb<4;kb++) hb[kb] = *(const bf16x8*)(hrow + kb*32 + kq);
    #pragma unroll
    for (int kb=0;kb<2;kb++) xb[kb] = *(const bf16x8*)(XT + (16*w + l15)*72 + kb*32 + kq);
    #pragma unroll
    for (int i=0;i<4;i++){
      f32x4 y2 = {};
      #pragma unroll
      for (int kb=0;kb<4;kb++){
        bf16x8 afr = *(const bf16x8*)(Cc + (16*i + l15)*136 + kb*32 + kq);
        y2 = __builtin_amdgcn_mfma_f32_16x16x32_bf16(afr, hb[kb], y2, 0,0,0);
      }
      f32x4 y1 = {};
      #pragma unroll
      for (int kb=0;kb<2;kb++){
        bf16x8 afr = *(const bf16x8*)(Bp + (16*i + l15)*72 + kb*32 + kq);
        y1 = __builtin_amdgcn_mfma_f32_16x16x32_bf16(afr, xb[kb], y1, 0,0,0);
      }
      int p = 16*w + l15;
      #pragma unroll
      for (int r=0;r<4;r++){
        int t = 16*i + quad*4 + r;
        float xv = bf2f(XT[p*72 + t]);
        yv[i][r] = y1[r] + els[t]*y2[r] + dph*xv;
      }
    }
  }
  // gate with silu(z)
  {
    const ushort* zcol = zxh + (size_t)(dtr0 + c0)*NZX + h*64 + (16*w + l15);
    #pragma unroll
    for (int i=0;i<4;i++)
      #pragma unroll
      for (int r=0;r<4;r++){
        int t = 16*i + quad*4 + r;
        float zz = bf2f(zcol[(size_t)t*NZX]);
        yv[i][r] *= zz / (1.f + expf(-zz));
      }
  }
  __syncthreads();                 // all Ps reads done; Bp becomes y-stage
  {
    int p = 16*w + l15;
    #pragma unroll
    for (int i=0;i<4;i++)
      #pragma unroll
      for (int r=0;r<4;r++)
        Bp[(16*i + quad*4 + r)*72 + p] = f2bf(yv[i][r]);
  }
  __syncthreads();
  { int t = tid >> 2, seg = tid & 3;
    uint4 a = *(const uint4*)(Bp + t*72 + seg*16);
    uint4 b = *(const uint4*)(Bp + t*72 + seg*16 + 8);
    ushort* od = xcv + (size_t)(c0 + t)*CONVDIM + h*64 + seg*16;
    *(uint4*)od = a;
    *(uint4*)(od + 8) = b;
    // per-(row, head) sumsq partial from bf16-rounded gated y
    const ushort* ya = (const ushort*)&a;
    const ushort* yb2 = (const ushort*)&b;
    float ss = 0.f;
    #pragma unroll
    for (int i=0;i<8;i++){ float v1 = bf2f(ya[i]); float v2 = bf2f(yb2[i]); ss = fmaf(v1,v1, fmaf(v2,v2, ss)); }
    ss += __shfl_xor(ss, 1);
    ss += __shfl_xor(ss, 2);
    if (seg == 0)
      dtraw[(size_t)(dtr0 + c0 + t)*128 + 64 + h] = ss;
  }
}

extern "C" void kernel_launch(void* const* d_in, const int* in_sizes, int n_in,
                              void* d_out, int out_size, void* d_ws, size_t ws_size,
                              hipStream_t stream) {
  const float* x    = (const float*)d_in[0];
  const float* ipw  = (const float*)d_in[1];
  const float* cw   = (const float*)d_in[2];
  const float* cb   = (const float*)d_in[3];
  const float* dtb  = (const float*)d_in[4];
  const float* alog = (const float*)d_in[5];
  const float* Dp   = (const float*)d_in[6];
  const float* nw   = (const float*)d_in[7];
  const float* opw  = (const float*)d_in[8];
  char* ws = (char*)d_ws;
  size_t off = 0;
  ushort* Wp    = (ushort*)(ws + off); off += (size_t)4480*DMODEL*2;     //  9.18 MB
  ushort* opwb  = (ushort*)(ws + off); off += (size_t)DMODEL*DINNER*2;   //  4.19 MB
  float*  dtraw = (float*)(ws + off);  off += (size_t)ROWS*128*4;        //  4.19 MB (cols 64..95 reused for RMS partials)
  ushort* zxbh  = (ushort*)(ws + off); off += (size_t)ROWS*NZX*2;        // 71.30 MB

  const size_t lg_b  = LGSEQ*4;                     //  0.52 MB per seq
  const size_t xc_b  = XCSEQ*2;                     // 18.87 MB per seq
  const size_t xc_fb = (size_t)1024*CONVDIM*2;      //  4.72 MB per chunk
  const size_t gb_b  = (size_t)NHEADS*NCS*8192*2;   // 33.55 MB per seq

  size_t needA = off + 2*lg_b + 2*xc_b + gb_b;      // ~161.2 MB (gbuf seq1 -> d_out)
  size_t needB = off + lg_b + xc_b + gb_b;          // ~141.8 MB
  int mode = (ws_size >= needA) ? 2 : (ws_size >= needB ? 1 : 0);

  float* lgbuf = (float*)(ws + off); off += (mode == 2) ? 2*lg_b : lg_b;
  ushort* xconv = (ushort*)(ws + off);
  off += (mode == 2) ? 2*xc_b : (mode == 1 ? xc_b : xc_fb);
  ushort* xbf  = (ushort*)(ws + off);               // dead after gemm1
  ushort* gbuf0 = (ushort*)(ws + off);              // overlays xbf
  ushort* gbuf1 = (mode == 2) ? (ushort*)d_out : gbuf0;   // seq1 state in d_out

  // one conversion launch: x (4096 blks) | padded in_proj_w (4480) | out_proj_w*nw (1024)
  cvt_all<<<9600, 256, 0, stream>>>((const float4*)x, (uint4*)xbf,
                                    (const float4*)ipw, (ushort4*)Wp,
                                    (const float4*)opw, (uint4*)opwb, nw);

  // merged in_proj GEMM incl dt columns: grid (35,64), nwg=2240 (q=280,r=0)
  gemm_tile<<<dim3(35, 64), 256, 0, stream>>>(
      xbf, DMODEL, 0, (long)ROWS-1, Wp, DMODEL,
      zxbh, NZX, DMODEL, 1, 1, 280, 0, dtraw, nullptr);

  if (mode == 2){
    conv8<<<dim3(288*(LL/4)/256, 2), 256, 0, stream>>>(zxbh, cw, cb, xconv, 0, 0);
    scan_pre2<<<dim3(NCS, NHEADS, 2), 256, 0, stream>>>(
        xconv, dtraw, 0, dtb, alog, gbuf0, gbuf1, lgbuf, 0);
    scan_carry2<<<dim3(4, NHEADS, 2), 256, 0, stream>>>(gbuf0, gbuf1, lgbuf, NCS);
    scan_y2<<<dim3(NCS, NHEADS, 2), 256, 0, stream>>>(
        xconv, zxbh, dtraw, 0, dtb, alog, lgbuf, gbuf0, gbuf1, Dp, 0);
    // out-proj with RMS scale fold: A = gated y in xconv (8192 contiguous rows)
    gemm_tile<<<dim3(8, 64), 256, 0, stream>>>(
        xconv, CONVDIM, 0, (long)ROWS-1, opwb, DINNER,
        (float*)d_out, DMODEL, DINNER, 0, 1, 64, 0, nullptr, dtraw + 64);
  } else if (mode == 1){
    for (int b = 0; b < 2; ++b){
      long row0 = (long)b*LL;
      conv8<<<dim3(288*(LL/4)/256, 1), 256, 0, stream>>>(zxbh, cw, cb, xconv, 0, row0);
      scan_pre2<<<dim3(NCS, NHEADS, 1), 256, 0, stream>>>(
          xconv, dtraw, row0, dtb, alog, gbuf0, gbuf0, lgbuf, 0);
      scan_carry2<<<dim3(4, NHEADS, 1), 256, 0, stream>>>(gbuf0, gbuf0, lgbuf, NCS);
      scan_y2<<<dim3(NCS, NHEADS, 1), 256, 0, stream>>>(
          xconv, zxbh, dtraw, row0, dtb, alog, lgbuf, gbuf0, gbuf0, Dp, 0);
      gemm_tile<<<dim3(8, 32), 256, 0, stream>>>(
          xconv, CONVDIM, 0, (long)LL-1, opwb, DINNER,
          (float*)d_out + (size_t)row0*DMODEL, DMODEL, DINNER, 0, 1, 32, 0,
          nullptr, dtraw + 64 + (size_t)row0*128);
    }
  } else {
    for (int b = 0; b < 2; ++b){
      long row0 = (long)b*LL;
      for (int ckl = 0; ckl < 4; ++ckl){
        long g0 = row0 + (long)ckl*1024;
        conv8<<<dim3(288*(1024/4)/256, 1), 256, 0, stream>>>(zxbh, cw, cb, xconv, ckl*1024, g0);
        scan_pre2<<<dim3(16, NHEADS, 1), 256, 0, stream>>>(
            xconv, dtraw, g0, dtb, alog, gbuf0, gbuf0, lgbuf, ckl*16);
      }
      scan_carry2<<<dim3(4, NHEADS, 1), 256, 0, stream>>>(gbuf0, gbuf0, lgbuf, NCS);
      for (int ckl = 0; ckl < 4; ++ckl){
        long g0 = row0 + (long)ckl*1024;
        conv8<<<dim3(288*(1024/4)/256, 1), 256, 0, stream>>>(zxbh, cw, cb, xconv, ckl*1024, g0);
        scan_y2<<<dim3(16, NHEADS, 1), 256, 0, stream>>>(
            xconv, zxbh, dtraw, g0, dtb, alog, lgbuf, gbuf0, gbuf0, Dp, ckl*16);
        gemm_tile<<<dim3(8, 8), 256, 0, stream>>>(
            xconv, CONVDIM, 0, 1023L, opwb, DINNER,
            (float*)d_out + (size_t)g0*DMODEL, DMODEL, DINNER, 0, 1, 8, 0,
            nullptr, dtraw + 64 + (size_t)g0*128);
      }
    }
  }
}